// Round 1
// baseline (16933.540 us; speedup 1.0000x reference)
//
#include <hip/hip_runtime.h>

#define TPB 256

// ---------------------------------------------------------------------------
// Direct convolution, NCHW, fp32. Each thread computes CO_T output channels
// for one (n, oh, ow) so every activation load feeds CO_T FMAs.
// Weight layout: w[COUT][CIN][K][K].
// ---------------------------------------------------------------------------
template<int CIN, int COUT, int HIN, int WIN, int K, int S, int P, int CO_T>
__global__ __launch_bounds__(TPB) void conv_fwd(
    const float* __restrict__ x, const float* __restrict__ w,
    const float* __restrict__ bias, float* __restrict__ y, int N)
{
    constexpr int HOUT = (HIN + 2 * P - K) / S + 1;
    constexpr int WOUT = (WIN + 2 * P - K) / S + 1;
    constexpr int NCOG = COUT / CO_T;
    int idx = blockIdx.x * TPB + threadIdx.x;
    int total = N * NCOG * HOUT * WOUT;
    if (idx >= total) return;
    int ow = idx % WOUT;
    int oh = (idx / WOUT) % HOUT;
    int cog = (idx / (WOUT * HOUT)) % NCOG;
    int n = idx / (WOUT * HOUT * NCOG);

    float acc[CO_T];
#pragma unroll
    for (int j = 0; j < CO_T; j++) acc[j] = bias[cog * CO_T + j];

    const float* xn = x + n * (CIN * HIN * WIN);
    const float* wg = w + cog * CO_T * (CIN * K * K);

    for (int ci = 0; ci < CIN; ci++) {
        const float* xc = xn + ci * (HIN * WIN);
#pragma unroll
        for (int kh = 0; kh < K; kh++) {
            int ih = oh * S - P + kh;
            if ((unsigned)ih >= (unsigned)HIN) continue;
#pragma unroll
            for (int kw = 0; kw < K; kw++) {
                int iw = ow * S - P + kw;
                if ((unsigned)iw >= (unsigned)WIN) continue;
                float v = xc[ih * WIN + iw];
#pragma unroll
                for (int j = 0; j < CO_T; j++)
                    acc[j] += v * wg[(j * CIN + ci) * (K * K) + kh * K + kw];
            }
        }
    }
    float* yp = y + ((n * COUT + cog * CO_T) * HOUT + oh) * WOUT + ow;
#pragma unroll
    for (int j = 0; j < CO_T; j++)
        yp[j * (HOUT * WOUT)] = acc[j];
}

// ---------------------------------------------------------------------------
// Transposed convolution (gather form), NCHW, fp32.
// torch ConvTranspose2d weight layout: w[CIN][COUT][K][K].
// y[oh,ow] += x[ih,iw]*w[..] where oh = ih*S - P + kh  =>  ih = (oh+P-kh)/S.
// ---------------------------------------------------------------------------
template<int CIN, int COUT, int HIN, int WIN, int K, int S, int P, int CO_T>
__global__ __launch_bounds__(TPB) void convt_fwd(
    const float* __restrict__ x, const float* __restrict__ w,
    const float* __restrict__ bias, float* __restrict__ y, int N)
{
    constexpr int HOUT = (HIN - 1) * S - 2 * P + K;
    constexpr int WOUT = (WIN - 1) * S - 2 * P + K;
    constexpr int NCOG = COUT / CO_T;
    int idx = blockIdx.x * TPB + threadIdx.x;
    int total = N * NCOG * HOUT * WOUT;
    if (idx >= total) return;
    int ow = idx % WOUT;
    int oh = (idx / WOUT) % HOUT;
    int cog = (idx / (WOUT * HOUT)) % NCOG;
    int n = idx / (WOUT * HOUT * NCOG);

    float acc[CO_T];
    int co0 = cog * CO_T;
#pragma unroll
    for (int j = 0; j < CO_T; j++) acc[j] = bias[co0 + j];

    const float* xn = x + n * (CIN * HIN * WIN);

#pragma unroll
    for (int kh = 0; kh < K; kh++) {
        int th = oh + P - kh;
        if (th < 0) continue;
        if (S > 1 && (th % S)) continue;
        int ih = th / S;
        if (ih >= HIN) continue;
#pragma unroll
        for (int kw = 0; kw < K; kw++) {
            int tw = ow + P - kw;
            if (tw < 0) continue;
            if (S > 1 && (tw % S)) continue;
            int iw = tw / S;
            if (iw >= WIN) continue;
            const float* xp = xn + ih * WIN + iw;
            for (int ci = 0; ci < CIN; ci++) {
                float v = xp[ci * (HIN * WIN)];
#pragma unroll
                for (int j = 0; j < CO_T; j++)
                    acc[j] += v * w[(ci * COUT + co0 + j) * (K * K) + kh * K + kw];
            }
        }
    }
    float* yp = y + ((n * COUT + co0) * HOUT + oh) * WOUT + ow;
#pragma unroll
    for (int j = 0; j < CO_T; j++)
        yp[j * (HOUT * WOUT)] = acc[j];
}

// ---------------------------------------------------------------------------
// BatchNorm stats: per-channel sum and sum-of-squares into stats[c], stats[C+c].
// stats region must be zeroed before launch. grid = (chunks, C).
// ---------------------------------------------------------------------------
template<int C, int HW>
__global__ __launch_bounds__(TPB) void bn_stats(
    const float* __restrict__ x, float* __restrict__ stats, int N)
{
    int c = blockIdx.y;
    int M = N * HW;
    float s = 0.f, sq = 0.f;
    for (int e = blockIdx.x * TPB + threadIdx.x; e < M; e += gridDim.x * TPB) {
        int n = e / HW;          // HW is a power of two -> shifts
        int p = e % HW;
        float v = x[(n * C + c) * HW + p];
        s += v;
        sq += v * v;
    }
    __shared__ float ss[TPB];
    __shared__ float ssq[TPB];
    ss[threadIdx.x] = s;
    ssq[threadIdx.x] = sq;
    __syncthreads();
    for (int off = TPB / 2; off > 0; off >>= 1) {
        if (threadIdx.x < off) {
            ss[threadIdx.x] += ss[threadIdx.x + off];
            ssq[threadIdx.x] += ssq[threadIdx.x + off];
        }
        __syncthreads();
    }
    if (threadIdx.x == 0) {
        atomicAdd(&stats[c], ss[0]);
        atomicAdd(&stats[C + c], ssq[0]);
    }
}

// ---------------------------------------------------------------------------
// In-place BN (training mode, biased var, eps=1e-5) + ReLU.
// ---------------------------------------------------------------------------
template<int C, int HW>
__global__ __launch_bounds__(TPB) void bn_apply_relu(
    float* __restrict__ y, const float* __restrict__ stats,
    const float* __restrict__ gamma, const float* __restrict__ beta, int N)
{
    int idx = blockIdx.x * TPB + threadIdx.x;
    int total = N * C * HW;
    if (idx >= total) return;
    int c = (idx / HW) % C;
    float cnt = (float)(N * HW);
    float m = stats[c] / cnt;
    float v = stats[C + c] / cnt - m * m;
    float sc = gamma[c] * rsqrtf(v + 1e-5f);
    float sh = beta[c] - m * sc;
    float val = y[idx] * sc + sh;
    y[idx] = val > 0.f ? val : 0.f;
}

// ---------------------------------------------------------------------------
// VQ: one block per (n,h,w) row. h layout is NCHW [128,256,16,16]; the row's
// channel vector lives at h[n*65536 + d*256 + pix]. Thread t computes squared
// distance to codebook row t; LDS argmin (first-index tie-break like
// jnp.argmin); overwrite row in-place with the chosen code; accumulate min
// distance (== ||Z-Wj||^2) into 64 partial-loss slots.
// ---------------------------------------------------------------------------
__global__ __launch_bounds__(TPB) void vq_kernel(
    float* __restrict__ h, const float* __restrict__ cb,
    float* __restrict__ lossp)
{
    int row = blockIdx.x;        // n*256 + pix
    int n = row >> 8;
    int pix = row & 255;
    int t = threadIdx.x;
    int base = n * 65536 + pix;

    __shared__ float zs[256];
    zs[t] = h[base + t * 256];
    __syncthreads();

    float acc = 0.f;
    const float* c = cb + t * 256;
    for (int d = 0; d < 256; d++) {
        float diff = zs[d] - c[d];
        acc += diff * diff;
    }

    __shared__ float sd[256];
    __shared__ int si[256];
    sd[t] = acc;
    si[t] = t;
    __syncthreads();
    for (int off = 128; off > 0; off >>= 1) {
        if (t < off) {
            float a = sd[t], b = sd[t + off];
            int ia = si[t], ib = si[t + off];
            if (b < a || (b == a && ib < ia)) { sd[t] = b; si[t] = ib; }
        }
        __syncthreads();
    }
    int j = si[0];
    if (t == 0) atomicAdd(&lossp[row & 63], sd[0]);
    h[base + t * 256] = cb[j * 256 + t];
}

__global__ __launch_bounds__(64) void loss_finalize(
    const float* __restrict__ lossp, float* __restrict__ out2)
{
    float v = lossp[threadIdx.x];
    for (int off = 32; off > 0; off >>= 1) v += __shfl_down(v, off);
    if (threadIdx.x == 0) {
        float m = v * (1.0f / 32768.0f);
        out2[0] = m;   // loss_commit
        out2[1] = m;   // loss_code (identical in forward)
    }
}

// ---------------------------------------------------------------------------

extern "C" void kernel_launch(void* const* d_in, const int* in_sizes, int n_in,
                              void* d_out, int out_size, void* d_ws, size_t ws_size,
                              hipStream_t stream) {
    const float* x    = (const float*)d_in[0];
    const float* cb   = (const float*)d_in[1];
    const float* e_w1 = (const float*)d_in[2];  const float* e_b1 = (const float*)d_in[3];
    const float* e_g1 = (const float*)d_in[4];  const float* e_be1 = (const float*)d_in[5];
    const float* e_w2 = (const float*)d_in[6];  const float* e_b2 = (const float*)d_in[7];
    const float* e_g2 = (const float*)d_in[8];  const float* e_be2 = (const float*)d_in[9];
    const float* e_w3 = (const float*)d_in[10]; const float* e_b3 = (const float*)d_in[11];
    const float* e_g3 = (const float*)d_in[12]; const float* e_be3 = (const float*)d_in[13];
    const float* e_w4 = (const float*)d_in[14]; const float* e_b4 = (const float*)d_in[15];
    const float* d_w1 = (const float*)d_in[16]; const float* d_b1 = (const float*)d_in[17];
    const float* d_g1 = (const float*)d_in[18]; const float* d_be1 = (const float*)d_in[19];
    const float* d_w2 = (const float*)d_in[20]; const float* d_b2 = (const float*)d_in[21];
    const float* d_g2 = (const float*)d_in[22]; const float* d_be2 = (const float*)d_in[23];
    const float* d_w3 = (const float*)d_in[24]; const float* d_b3 = (const float*)d_in[25];
    const float* d_g3 = (const float*)d_in[26]; const float* d_be3 = (const float*)d_in[27];
    const float* d_w4 = (const float*)d_in[28]; const float* d_b4 = (const float*)d_in[29];

    float* ws = (float*)d_ws;
    // Region A (33,554,432 floats = 134.2 MB): h1, then {h3, h4/hq, g1}, then g3.
    // Region B (16,777,216 floats = 67.1 MB): h2, then g2.
    float* A = ws;
    float* B = ws + 33554432;
    float* stats = ws + 50331648;        // 6 layers x 512 floats
    float* lossp = stats + 3072;         // 64 partial-loss slots
    float* h1 = A;
    float* h2 = B;
    float* h3 = A;
    float* h4 = A + 6291456;             // also hq (in-place VQ)
    float* g1 = A + 14680064;
    float* g2 = B;
    float* g3 = A;
    float* out = (float*)d_out;
    float* losses = out + 1572864;

    const int N = 128;

    hipMemsetAsync(stats, 0, (3072 + 64) * sizeof(float), stream);

    // ---- encoder L1: conv 3x3 s1 p1, 3->64, 64x64 ----
    {
        int total = N * (64 / 8) * 64 * 64;
        conv_fwd<3, 64, 64, 64, 3, 1, 1, 8><<<(total + TPB - 1) / TPB, TPB, 0, stream>>>(x, e_w1, e_b1, h1, N);
        dim3 g(64, 64);
        bn_stats<64, 4096><<<g, TPB, 0, stream>>>(h1, stats + 0 * 512, N);
        int te = N * 64 * 4096;
        bn_apply_relu<64, 4096><<<(te + TPB - 1) / TPB, TPB, 0, stream>>>(h1, stats + 0 * 512, e_g1, e_be1, N);
    }
    // ---- encoder L2: conv 4x4 s2 p1, 64->128, ->32x32 ----
    {
        int total = N * (128 / 8) * 32 * 32;
        conv_fwd<64, 128, 64, 64, 4, 2, 1, 8><<<(total + TPB - 1) / TPB, TPB, 0, stream>>>(h1, e_w2, e_b2, h2, N);
        dim3 g(16, 128);
        bn_stats<128, 1024><<<g, TPB, 0, stream>>>(h2, stats + 1 * 512, N);
        int te = N * 128 * 1024;
        bn_apply_relu<128, 1024><<<(te + TPB - 1) / TPB, TPB, 0, stream>>>(h2, stats + 1 * 512, e_g2, e_be2, N);
    }
    // ---- encoder L3: conv 4x4 s2 p1, 128->192, ->16x16 ----
    {
        int total = N * (192 / 8) * 16 * 16;
        conv_fwd<128, 192, 32, 32, 4, 2, 1, 8><<<(total + TPB - 1) / TPB, TPB, 0, stream>>>(h2, e_w3, e_b3, h3, N);
        dim3 g(8, 192);
        bn_stats<192, 256><<<g, TPB, 0, stream>>>(h3, stats + 2 * 512, N);
        int te = N * 192 * 256;
        bn_apply_relu<192, 256><<<(te + TPB - 1) / TPB, TPB, 0, stream>>>(h3, stats + 2 * 512, e_g3, e_be3, N);
    }
    // ---- encoder L4: conv 1x1, 192->256 ----
    {
        int total = N * (256 / 8) * 16 * 16;
        conv_fwd<192, 256, 16, 16, 1, 1, 0, 8><<<(total + TPB - 1) / TPB, TPB, 0, stream>>>(h3, e_w4, e_b4, h4, N);
    }
    // ---- VQ (in-place on h4) + losses ----
    vq_kernel<<<32768, TPB, 0, stream>>>(h4, cb, lossp);
    loss_finalize<<<1, 64, 0, stream>>>(lossp, losses);

    // ---- decoder D1: convT 1x1, 256->192 ----
    {
        int total = N * (192 / 8) * 16 * 16;
        convt_fwd<256, 192, 16, 16, 1, 1, 0, 8><<<(total + TPB - 1) / TPB, TPB, 0, stream>>>(h4, d_w1, d_b1, g1, N);
        dim3 g(8, 192);
        bn_stats<192, 256><<<g, TPB, 0, stream>>>(g1, stats + 3 * 512, N);
        int te = N * 192 * 256;
        bn_apply_relu<192, 256><<<(te + TPB - 1) / TPB, TPB, 0, stream>>>(g1, stats + 3 * 512, d_g1, d_be1, N);
    }
    // ---- decoder D2: convT 4x4 s2 p1, 192->128, ->32x32 ----
    {
        int total = N * (128 / 8) * 32 * 32;
        convt_fwd<192, 128, 16, 16, 4, 2, 1, 8><<<(total + TPB - 1) / TPB, TPB, 0, stream>>>(g1, d_w2, d_b2, g2, N);
        dim3 g(16, 128);
        bn_stats<128, 1024><<<g, TPB, 0, stream>>>(g2, stats + 4 * 512, N);
        int te = N * 128 * 1024;
        bn_apply_relu<128, 1024><<<(te + TPB - 1) / TPB, TPB, 0, stream>>>(g2, stats + 4 * 512, d_g2, d_be2, N);
    }
    // ---- decoder D3: convT 4x4 s2 p1, 128->64, ->64x64 ----
    {
        int total = N * (64 / 8) * 64 * 64;
        convt_fwd<128, 64, 32, 32, 4, 2, 1, 8><<<(total + TPB - 1) / TPB, TPB, 0, stream>>>(g2, d_w3, d_b3, g3, N);
        dim3 g(64, 64);
        bn_stats<64, 4096><<<g, TPB, 0, stream>>>(g3, stats + 5 * 512, N);
        int te = N * 64 * 4096;
        bn_apply_relu<64, 4096><<<(te + TPB - 1) / TPB, TPB, 0, stream>>>(g3, stats + 5 * 512, d_g3, d_be3, N);
    }
    // ---- decoder D4: conv 3x3 s1 p1, 64->3 -> d_out ----
    {
        int total = N * (3 / 3) * 64 * 64;
        conv_fwd<64, 3, 64, 64, 3, 1, 1, 3><<<(total + TPB - 1) / TPB, TPB, 0, stream>>>(g3, d_w4, d_b4, out, N);
    }
}

// Round 2
// 4614.309 us; speedup vs baseline: 3.6698x; 3.6698x over previous
//
#include <hip/hip_runtime.h>

#define TPB 256

// ---------------------------------------------------------------------------
// Direct convolution, NCHW, fp32, LDS-staged weights, 4 pixels/thread.
// WLAYOUT 0: w[COUT][CIN][K][K] (normal conv)
// WLAYOUT 1: w[CIN][COUT][K][K] (used for 1x1 ConvTranspose)
// LDS layout: wlds[kk][ci][CO_T]
// ---------------------------------------------------------------------------
template<int CIN, int COUT, int HIN, int WIN, int K, int S, int P, int CO_T,
         int CI_CHUNK, int WLAYOUT>
__global__ __launch_bounds__(TPB) void conv_fwd(
    const float* __restrict__ x, const float* __restrict__ w,
    const float* __restrict__ bias, float* __restrict__ y, int N)
{
    constexpr int HOUT = (HIN + 2 * P - K) / S + 1;
    constexpr int WOUT = (WIN + 2 * P - K) / S + 1;
    constexpr int HW_IN = HIN * WIN;
    constexpr int PIX_T = 4;
    __shared__ float wlds[K * K * CI_CHUNK * CO_T];

    const int t = threadIdx.x;
    const int co0 = blockIdx.y * CO_T;
    const int total = N * HOUT * WOUT;

    int n_[PIX_T], oh_[PIX_T], ow_[PIX_T];
    bool pval[PIX_T];
    const float* xb[PIX_T];
#pragma unroll
    for (int p = 0; p < PIX_T; p++) {
        int q = blockIdx.x * (TPB * PIX_T) + p * TPB + t;
        pval[p] = q < total;
        int qq = pval[p] ? q : 0;
        ow_[p] = qq % WOUT;
        oh_[p] = (qq / WOUT) % HOUT;
        n_[p] = qq / (WOUT * HOUT);
        xb[p] = x + (size_t)n_[p] * CIN * HW_IN;
    }

    float acc[PIX_T][CO_T];
#pragma unroll
    for (int p = 0; p < PIX_T; p++)
#pragma unroll
        for (int j = 0; j < CO_T; j++) acc[p][j] = bias[co0 + j];

    for (int ci0 = 0; ci0 < CIN; ci0 += CI_CHUNK) {
        __syncthreads();
        for (int i = t; i < K * K * CI_CHUNK * CO_T; i += TPB) {
            int j = i % CO_T;
            int ci = (i / CO_T) % CI_CHUNK;
            int kk = i / (CO_T * CI_CHUNK);
            float wv;
            if (WLAYOUT == 0)
                wv = w[((size_t)(co0 + j) * CIN + (ci0 + ci)) * (K * K) + kk];
            else
                wv = w[((size_t)(ci0 + ci) * COUT + (co0 + j)) * (K * K) + kk];
            wlds[i] = wv;
        }
        __syncthreads();

#pragma unroll
        for (int kh = 0; kh < K; kh++) {
#pragma unroll
            for (int kw = 0; kw < K; kw++) {
                const float* xp[PIX_T];
                bool v[PIX_T];
#pragma unroll
                for (int p = 0; p < PIX_T; p++) {
                    int ih = oh_[p] * S - P + kh;
                    int iw = ow_[p] * S - P + kw;
                    v[p] = pval[p] && (unsigned)ih < (unsigned)HIN &&
                           (unsigned)iw < (unsigned)WIN;
                    int off = v[p] ? (ih * WIN + iw) : 0;
                    xp[p] = xb[p] + (size_t)ci0 * HW_IN + off;
                }
                const float* wp = &wlds[(kh * K + kw) * CI_CHUNK * CO_T];
                for (int ci = 0; ci < CI_CHUNK; ci++) {
                    float xv[PIX_T];
#pragma unroll
                    for (int p = 0; p < PIX_T; p++)
                        xv[p] = v[p] ? xp[p][(size_t)ci * HW_IN] : 0.f;
#pragma unroll
                    for (int j = 0; j < CO_T; j++) {
                        float wv = wp[ci * CO_T + j];
#pragma unroll
                        for (int p = 0; p < PIX_T; p++)
                            acc[p][j] += xv[p] * wv;
                    }
                }
            }
        }
    }

#pragma unroll
    for (int p = 0; p < PIX_T; p++) {
        if (!pval[p]) continue;
        float* yp = y + ((size_t)n_[p] * COUT + co0) * (HOUT * WOUT) +
                    oh_[p] * WOUT + ow_[p];
#pragma unroll
        for (int j = 0; j < CO_T; j++)
            yp[(size_t)j * (HOUT * WOUT)] = acc[p][j];
    }
}

// ---------------------------------------------------------------------------
// Transposed conv, stride 2, K=4, P=1 (gather form), parity-decomposed.
// blockIdx.z = class (oh%2)*2 + (ow%2); the valid 2x2 tap set is
// block-uniform so no wasted taps. torch weight layout w[CIN][COUT][4][4].
// y[n,co,oh,ow] = sum_ci x[n,ci,ih,iw]*w[ci][co][kh][kw], oh = ih*2-1+kh.
// ---------------------------------------------------------------------------
template<int CIN, int COUT, int HIN, int WIN, int CO_T, int CI_CHUNK>
__global__ __launch_bounds__(TPB) void convt2(
    const float* __restrict__ x, const float* __restrict__ w,
    const float* __restrict__ bias, float* __restrict__ y, int N)
{
    constexpr int HOUT = HIN * 2;
    constexpr int WOUT = WIN * 2;
    constexpr int HW_IN = HIN * WIN;
    constexpr int PIX_T = 4;
    __shared__ float wlds[4 * CI_CHUNK * CO_T];

    const int t = threadIdx.x;
    const int co0 = blockIdx.y * CO_T;
    const int ohp = blockIdx.z >> 1, owp = blockIdx.z & 1;
    const int kh_base = (ohp + 1) & 1, kw_base = (owp + 1) & 1;
    const int dh0 = (ohp + 1 - kh_base) >> 1;  // ih = i + dh, dh in {dh0, dh0-1}
    const int dw0 = (owp + 1 - kw_base) >> 1;
    const int total = N * HIN * WIN;  // class-space pixels

    int n_[PIX_T], i_[PIX_T], j_[PIX_T];
    bool pval[PIX_T];
    const float* xb[PIX_T];
#pragma unroll
    for (int p = 0; p < PIX_T; p++) {
        int q = blockIdx.x * (TPB * PIX_T) + p * TPB + t;
        pval[p] = q < total;
        int qq = pval[p] ? q : 0;
        j_[p] = qq % WIN;
        i_[p] = (qq / WIN) % HIN;
        n_[p] = qq / (WIN * HIN);
        xb[p] = x + (size_t)n_[p] * CIN * HW_IN;
    }

    float acc[PIX_T][CO_T];
#pragma unroll
    for (int p = 0; p < PIX_T; p++)
#pragma unroll
        for (int j = 0; j < CO_T; j++) acc[p][j] = bias[co0 + j];

    for (int ci0 = 0; ci0 < CIN; ci0 += CI_CHUNK) {
        __syncthreads();
        for (int i = t; i < 4 * CI_CHUNK * CO_T; i += TPB) {
            int j = i % CO_T;
            int ci = (i / CO_T) % CI_CHUNK;
            int kidx = i / (CO_T * CI_CHUNK);
            int kh = kh_base + ((kidx >> 1) << 1);
            int kw = kw_base + ((kidx & 1) << 1);
            wlds[i] = w[((size_t)(ci0 + ci) * COUT + (co0 + j)) * 16 + kh * 4 + kw];
        }
        __syncthreads();

#pragma unroll
        for (int kidx = 0; kidx < 4; kidx++) {
            const int dh = (kidx >> 1) ? (dh0 - 1) : dh0;
            const int dw = (kidx & 1) ? (dw0 - 1) : dw0;
            const float* xp[PIX_T];
            bool v[PIX_T];
#pragma unroll
            for (int p = 0; p < PIX_T; p++) {
                int ih = i_[p] + dh;
                int iw = j_[p] + dw;
                v[p] = pval[p] && (unsigned)ih < (unsigned)HIN &&
                       (unsigned)iw < (unsigned)WIN;
                int off = v[p] ? (ih * WIN + iw) : 0;
                xp[p] = xb[p] + (size_t)ci0 * HW_IN + off;
            }
            const float* wp = &wlds[kidx * CI_CHUNK * CO_T];
            for (int ci = 0; ci < CI_CHUNK; ci++) {
                float xv[PIX_T];
#pragma unroll
                for (int p = 0; p < PIX_T; p++)
                    xv[p] = v[p] ? xp[p][(size_t)ci * HW_IN] : 0.f;
#pragma unroll
                for (int j = 0; j < CO_T; j++) {
                    float wv = wp[ci * CO_T + j];
#pragma unroll
                    for (int p = 0; p < PIX_T; p++)
                        acc[p][j] += xv[p] * wv;
                }
            }
        }
    }

#pragma unroll
    for (int p = 0; p < PIX_T; p++) {
        if (!pval[p]) continue;
        int oh = 2 * i_[p] + ohp, ow = 2 * j_[p] + owp;
        float* yp = y + ((size_t)n_[p] * COUT + co0) * (HOUT * WOUT) +
                    oh * WOUT + ow;
#pragma unroll
        for (int j = 0; j < CO_T; j++)
            yp[(size_t)j * (HOUT * WOUT)] = acc[p][j];
    }
}

// ---------------------------------------------------------------------------
// BatchNorm stats: per-channel sum / sum-of-squares (atomic into zeroed ws).
// ---------------------------------------------------------------------------
template<int C, int HW>
__global__ __launch_bounds__(TPB) void bn_stats(
    const float* __restrict__ x, float* __restrict__ stats, int N)
{
    int c = blockIdx.y;
    int M = N * HW;
    float s = 0.f, sq = 0.f;
    for (int e = blockIdx.x * TPB + threadIdx.x; e < M; e += gridDim.x * TPB) {
        int n = e / HW;
        int p = e % HW;
        float v = x[(size_t)(n * C + c) * HW + p];
        s += v;
        sq += v * v;
    }
    __shared__ float ss[TPB];
    __shared__ float ssq[TPB];
    ss[threadIdx.x] = s;
    ssq[threadIdx.x] = sq;
    __syncthreads();
    for (int off = TPB / 2; off > 0; off >>= 1) {
        if (threadIdx.x < off) {
            ss[threadIdx.x] += ss[threadIdx.x + off];
            ssq[threadIdx.x] += ssq[threadIdx.x + off];
        }
        __syncthreads();
    }
    if (threadIdx.x == 0) {
        atomicAdd(&stats[c], ss[0]);
        atomicAdd(&stats[C + c], ssq[0]);
    }
}

template<int C, int HW>
__global__ __launch_bounds__(TPB) void bn_apply_relu(
    float* __restrict__ y, const float* __restrict__ stats,
    const float* __restrict__ gamma, const float* __restrict__ beta, int N)
{
    int idx = blockIdx.x * TPB + threadIdx.x;
    int total = N * C * HW;
    if (idx >= total) return;
    int c = (idx / HW) % C;
    float cnt = (float)(N * HW);
    float m = stats[c] / cnt;
    float v = stats[C + c] / cnt - m * m;
    float sc = gamma[c] * rsqrtf(v + 1e-5f);
    float sh = beta[c] - m * sc;
    float val = y[idx] * sc + sh;
    y[idx] = val > 0.f ? val : 0.f;
}

// ---------------------------------------------------------------------------
// Codebook transpose: cbT[d*256 + c] = cb[c*256 + d]  (256x256)
// ---------------------------------------------------------------------------
__global__ __launch_bounds__(TPB) void cb_transpose(
    const float* __restrict__ cb, float* __restrict__ cbT)
{
    int idx = blockIdx.x * TPB + threadIdx.x;
    int d = idx >> 8, c = idx & 255;
    cbT[idx] = cb[c * 256 + d];
}

// ---------------------------------------------------------------------------
// VQ: one block per (n,pix) row. Thread t = code t. Distance loop reads the
// transposed codebook (coalesced, L2-hot). First-index tie-break argmin.
// Overwrites the row in-place with the selected code; min distance summed
// into 64 partial-loss slots.
// ---------------------------------------------------------------------------
__global__ __launch_bounds__(TPB) void vq_kernel(
    float* __restrict__ h, const float* __restrict__ cbT,
    const float* __restrict__ cb, float* __restrict__ lossp)
{
    int row = blockIdx.x;  // n*256 + pix
    int n = row >> 8;
    int pix = row & 255;
    int t = threadIdx.x;
    size_t base = (size_t)n * 65536 + pix;

    __shared__ float zs[256];
    zs[t] = h[base + (size_t)t * 256];
    __syncthreads();

    float acc = 0.f;
#pragma unroll 4
    for (int d = 0; d < 256; d++) {
        float diff = zs[d] - cbT[d * 256 + t];
        acc += diff * diff;
    }

    __shared__ float sd[256];
    __shared__ int si[256];
    sd[t] = acc;
    si[t] = t;
    __syncthreads();
    for (int off = 128; off > 0; off >>= 1) {
        if (t < off) {
            float a = sd[t], b = sd[t + off];
            int ia = si[t], ib = si[t + off];
            if (b < a || (b == a && ib < ia)) { sd[t] = b; si[t] = ib; }
        }
        __syncthreads();
    }
    int j = si[0];
    if (t == 0) atomicAdd(&lossp[row & 63], sd[0]);
    h[base + (size_t)t * 256] = cb[j * 256 + t];
}

__global__ __launch_bounds__(64) void loss_finalize(
    const float* __restrict__ lossp, float* __restrict__ out2)
{
    float v = lossp[threadIdx.x];
    for (int off = 32; off > 0; off >>= 1) v += __shfl_down(v, off);
    if (threadIdx.x == 0) {
        float m = v * (1.0f / 32768.0f);
        out2[0] = m;   // loss_commit
        out2[1] = m;   // loss_code (identical in forward)
    }
}

// ---------------------------------------------------------------------------

extern "C" void kernel_launch(void* const* d_in, const int* in_sizes, int n_in,
                              void* d_out, int out_size, void* d_ws, size_t ws_size,
                              hipStream_t stream) {
    const float* x    = (const float*)d_in[0];
    const float* cb   = (const float*)d_in[1];
    const float* e_w1 = (const float*)d_in[2];  const float* e_b1 = (const float*)d_in[3];
    const float* e_g1 = (const float*)d_in[4];  const float* e_be1 = (const float*)d_in[5];
    const float* e_w2 = (const float*)d_in[6];  const float* e_b2 = (const float*)d_in[7];
    const float* e_g2 = (const float*)d_in[8];  const float* e_be2 = (const float*)d_in[9];
    const float* e_w3 = (const float*)d_in[10]; const float* e_b3 = (const float*)d_in[11];
    const float* e_g3 = (const float*)d_in[12]; const float* e_be3 = (const float*)d_in[13];
    const float* e_w4 = (const float*)d_in[14]; const float* e_b4 = (const float*)d_in[15];
    const float* d_w1 = (const float*)d_in[16]; const float* d_b1 = (const float*)d_in[17];
    const float* d_g1 = (const float*)d_in[18]; const float* d_be1 = (const float*)d_in[19];
    const float* d_w2 = (const float*)d_in[20]; const float* d_b2 = (const float*)d_in[21];
    const float* d_g2 = (const float*)d_in[22]; const float* d_be2 = (const float*)d_in[23];
    const float* d_w3 = (const float*)d_in[24]; const float* d_b3 = (const float*)d_in[25];
    const float* d_g3 = (const float*)d_in[26]; const float* d_be3 = (const float*)d_in[27];
    const float* d_w4 = (const float*)d_in[28]; const float* d_b4 = (const float*)d_in[29];

    float* ws = (float*)d_ws;
    // Region A (33,554,432 floats): h1 -> {h3, h4/hq, g1} -> g3.
    // Region B (16,777,216 floats): h2 -> cbT -> g2.
    float* A = ws;
    float* B = ws + 33554432;
    float* stats = ws + 50331648;        // 6 layers x 512 floats
    float* lossp = stats + 3072;         // 64 partial-loss slots
    float* h1 = A;
    float* h2 = B;
    float* h3 = A;
    float* h4 = A + 6291456;             // also hq (in-place VQ)
    float* g1 = A + 14680064;
    float* cbT = B;                      // h2 is dead after encoder L3
    float* g2 = B;                       // cbT dead after vq
    float* g3 = A;
    float* out = (float*)d_out;
    float* losses = out + 1572864;

    const int N = 128;

    hipMemsetAsync(stats, 0, (3072 + 64) * sizeof(float), stream);

    // ---- encoder L1: conv 3x3 s1 p1, 3->64, 64x64 ----
    {
        conv_fwd<3, 64, 64, 64, 3, 1, 1, 8, 3, 0>
            <<<dim3(512, 8), TPB, 0, stream>>>(x, e_w1, e_b1, h1, N);
        bn_stats<64, 4096><<<dim3(64, 64), TPB, 0, stream>>>(h1, stats + 0 * 512, N);
        int te = N * 64 * 4096;
        bn_apply_relu<64, 4096><<<(te + TPB - 1) / TPB, TPB, 0, stream>>>(h1, stats + 0 * 512, e_g1, e_be1, N);
    }
    // ---- encoder L2: conv 4x4 s2 p1, 64->128, ->32x32 ----
    {
        conv_fwd<64, 128, 64, 64, 4, 2, 1, 8, 64, 0>
            <<<dim3(128, 16), TPB, 0, stream>>>(h1, e_w2, e_b2, h2, N);
        bn_stats<128, 1024><<<dim3(16, 128), TPB, 0, stream>>>(h2, stats + 1 * 512, N);
        int te = N * 128 * 1024;
        bn_apply_relu<128, 1024><<<(te + TPB - 1) / TPB, TPB, 0, stream>>>(h2, stats + 1 * 512, e_g2, e_be2, N);
    }
    // ---- encoder L3: conv 4x4 s2 p1, 128->192, ->16x16 ----
    {
        conv_fwd<128, 192, 32, 32, 4, 2, 1, 8, 64, 0>
            <<<dim3(32, 24), TPB, 0, stream>>>(h2, e_w3, e_b3, h3, N);
        bn_stats<192, 256><<<dim3(8, 192), TPB, 0, stream>>>(h3, stats + 2 * 512, N);
        int te = N * 192 * 256;
        bn_apply_relu<192, 256><<<(te + TPB - 1) / TPB, TPB, 0, stream>>>(h3, stats + 2 * 512, e_g3, e_be3, N);
    }
    // ---- encoder L4: conv 1x1, 192->256 ----
    conv_fwd<192, 256, 16, 16, 1, 1, 0, 8, 192, 0>
        <<<dim3(32, 32), TPB, 0, stream>>>(h3, e_w4, e_b4, h4, N);

    // ---- VQ (in-place on h4) + losses ----
    cb_transpose<<<256, TPB, 0, stream>>>(cb, cbT);
    vq_kernel<<<32768, TPB, 0, stream>>>(h4, cbT, cb, lossp);
    loss_finalize<<<1, 64, 0, stream>>>(lossp, losses);

    // ---- decoder D1: convT 1x1, 256->192 (== 1x1 conv, w[ci][co]) ----
    {
        conv_fwd<256, 192, 16, 16, 1, 1, 0, 8, 256, 1>
            <<<dim3(32, 24), TPB, 0, stream>>>(h4, d_w1, d_b1, g1, N);
        bn_stats<192, 256><<<dim3(8, 192), TPB, 0, stream>>>(g1, stats + 3 * 512, N);
        int te = N * 192 * 256;
        bn_apply_relu<192, 256><<<(te + TPB - 1) / TPB, TPB, 0, stream>>>(g1, stats + 3 * 512, d_g1, d_be1, N);
    }
    // ---- decoder D2: convT 4x4 s2 p1, 192->128, ->32x32 ----
    {
        convt2<192, 128, 16, 16, 8, 64>
            <<<dim3(32, 16, 4), TPB, 0, stream>>>(g1, d_w2, d_b2, g2, N);
        bn_stats<128, 1024><<<dim3(16, 128), TPB, 0, stream>>>(g2, stats + 4 * 512, N);
        int te = N * 128 * 1024;
        bn_apply_relu<128, 1024><<<(te + TPB - 1) / TPB, TPB, 0, stream>>>(g2, stats + 4 * 512, d_g2, d_be2, N);
    }
    // ---- decoder D3: convT 4x4 s2 p1, 128->64, ->64x64 ----
    {
        convt2<128, 64, 32, 32, 8, 64>
            <<<dim3(128, 8, 4), TPB, 0, stream>>>(g2, d_w3, d_b3, g3, N);
        bn_stats<64, 4096><<<dim3(64, 64), TPB, 0, stream>>>(g3, stats + 5 * 512, N);
        int te = N * 64 * 4096;
        bn_apply_relu<64, 4096><<<(te + TPB - 1) / TPB, TPB, 0, stream>>>(g3, stats + 5 * 512, d_g3, d_be3, N);
    }
    // ---- decoder D4: conv 3x3 s1 p1, 64->3 -> d_out ----
    conv_fwd<64, 3, 64, 64, 3, 1, 1, 3, 64, 0>
        <<<dim3(512, 1), TPB, 0, stream>>>(g3, d_w4, d_b4, out, N);
}

// Round 3
// 1726.417 us; speedup vs baseline: 9.8085x; 2.6728x over previous
//
#include <hip/hip_runtime.h>

#define TPB 256

typedef __attribute__((ext_vector_type(4))) float v4f;
typedef __attribute__((ext_vector_type(8))) short v8s;

__device__ __forceinline__ float us2f(unsigned int u) {
    union { unsigned int i; float f; } w; w.i = u << 16; return w.f;
}
__device__ __forceinline__ unsigned short f2us(float f) {
    union { float ff; unsigned int i; } w; w.ff = f;
    unsigned int u = w.i;
    return (unsigned short)((u + 0x7fffu + ((u >> 16) & 1u)) >> 16);
}

// ---------------------------------------------------------------------------
// Weight repacks (fp32 -> bf16, GEMM-friendly [tap][co][ci])
// ---------------------------------------------------------------------------
// conv weight [COUT][CIN][KK] -> [KK][COUT][CIN]
template<int CIN, int COUT, int KK>
__global__ __launch_bounds__(TPB) void repack_w(
    const float* __restrict__ w, unsigned short* __restrict__ o)
{
    int idx = blockIdx.x * TPB + threadIdx.x;
    if (idx >= KK * COUT * CIN) return;
    int ci = idx % CIN;
    int co = (idx / CIN) % COUT;
    int kk = idx / (CIN * COUT);
    o[idx] = f2us(w[((size_t)co * CIN + ci) * KK + kk]);
}
// 1x1 convT weight [CIN][COUT] -> [COUT][CIN]
template<int CIN, int COUT>
__global__ __launch_bounds__(TPB) void repack_wt1(
    const float* __restrict__ w, unsigned short* __restrict__ o)
{
    int idx = blockIdx.x * TPB + threadIdx.x;
    if (idx >= CIN * COUT) return;
    int ci = idx % CIN;
    int co = idx / CIN;
    o[idx] = f2us(w[(size_t)ci * COUT + co]);
}
// convT k4 s2 p1 weight [CIN][COUT][4][4] -> [cls][kidx][COUT][CIN]
// (parity math identical to the round-2 convt2 that passed)
template<int CIN, int COUT>
__global__ __launch_bounds__(TPB) void repack_wct(
    const float* __restrict__ w, unsigned short* __restrict__ o)
{
    int idx = blockIdx.x * TPB + threadIdx.x;
    if (idx >= 16 * COUT * CIN) return;
    int ci = idx % CIN;
    int co = (idx / CIN) % COUT;
    int kidx = (idx / (CIN * COUT)) & 3;
    int cls = idx / (CIN * COUT * 4);
    int ohp = cls >> 1, owp = cls & 1;
    int kh = ((ohp + 1) & 1) + 2 * (kidx >> 1);
    int kw = ((owp + 1) & 1) + 2 * (kidx & 1);
    o[idx] = f2us(w[((size_t)ci * COUT + co) * 16 + kh * 4 + kw]);
}

// ---------------------------------------------------------------------------
// Encoder L1: direct conv 3->64, k3 s1 p1, reads NCHW fp32 x, writes NHWC bf16.
// ---------------------------------------------------------------------------
__global__ __launch_bounds__(TPB) void conv_e1(
    const float* __restrict__ x, const float* __restrict__ w,
    const float* __restrict__ bias, unsigned short* __restrict__ y, int N)
{
    __shared__ float wl[27][64];
    int t = threadIdx.x;
    for (int i = t; i < 27 * 64; i += TPB) {
        int co = i & 63;
        int tap = i >> 6;          // ci*9 + kh*3 + kw
        int ci = tap / 9, kk = tap % 9;
        wl[tap][co] = w[((size_t)co * 3 + ci) * 9 + kk];
    }
    __syncthreads();
    int p = blockIdx.x * TPB + t;          // pixel index, N*4096 total
    int n = p >> 12, oh = (p >> 6) & 63, ow = p & 63;
    float acc[64];
#pragma unroll
    for (int co = 0; co < 64; co++) acc[co] = bias[co];
    for (int ci = 0; ci < 3; ci++) {
#pragma unroll
        for (int kh = 0; kh < 3; kh++) {
            int ih = oh - 1 + kh;
            if ((unsigned)ih >= 64u) continue;
#pragma unroll
            for (int kw = 0; kw < 3; kw++) {
                int iw = ow - 1 + kw;
                if ((unsigned)iw >= 64u) continue;
                float xv = x[(((size_t)n * 3 + ci) * 64 + ih) * 64 + iw];
                int tap = ci * 9 + kh * 3 + kw;
#pragma unroll
                for (int co = 0; co < 64; co++) acc[co] += xv * wl[tap][co];
            }
        }
    }
    unsigned int* yp = (unsigned int*)(y + (size_t)p * 64);
#pragma unroll
    for (int co = 0; co < 64; co += 2)
        yp[co >> 1] = (unsigned int)f2us(acc[co]) | ((unsigned int)f2us(acc[co + 1]) << 16);
}

// ---------------------------------------------------------------------------
// MFMA implicit-GEMM conv. NHWC bf16 in, [KK][COUT][CIN] bf16 weights.
// Tile: 128 rows x BN cols, 4 waves (2x2), BK=32 via mfma_f32_16x16x32_bf16.
// OUT_F32=1 writes fp32 (for the VQ input), else bf16.
// ---------------------------------------------------------------------------
template<int CIN, int COUT, int HIN, int WIN, int K, int S, int P, int BN, int OUT_F32>
__global__ __launch_bounds__(TPB) void conv_mfma(
    const unsigned short* __restrict__ xin, const unsigned short* __restrict__ wrep,
    const float* __restrict__ bias, void* __restrict__ yout, int N)
{
    constexpr int HOUT = (HIN + 2 * P - K) / S + 1;
    constexpr int WOUT = (WIN + 2 * P - K) / S + 1;
    constexpr int LDA = 40;              // 32 + 8 pad (2-way bank alias = free)
    constexpr int RN = BN / 32;
    __shared__ __align__(16) unsigned short Ab[128 * LDA];
    __shared__ __align__(16) unsigned short Bb[BN * LDA];

    const int t = threadIdx.x, lane = t & 63, wave = t >> 6;
    const int wm = wave >> 1, wn = wave & 1;
    const int m0 = blockIdx.x * 128, co0 = blockIdx.y * BN;
    const int q = t & 3;

    int n_[2], oh_[2], ow_[2];
#pragma unroll
    for (int i = 0; i < 2; i++) {
        int r = m0 + (t >> 2) + i * 64;
        n_[i] = r / (HOUT * WOUT);
        int rem = r % (HOUT * WOUT);
        oh_[i] = rem / WOUT;
        ow_[i] = rem % WOUT;
    }

    v4f acc[4][RN];
#pragma unroll
    for (int i = 0; i < 4; i++)
#pragma unroll
        for (int j = 0; j < RN; j++)
#pragma unroll
            for (int r = 0; r < 4; r++) acc[i][j][r] = 0.f;

    for (int kk = 0; kk < K * K; kk++) {
        const int kh = kk / K, kw = kk % K;
        size_t abase[2];
        bool avld[2];
#pragma unroll
        for (int i = 0; i < 2; i++) {
            int ih = oh_[i] * S - P + kh;
            int iw = ow_[i] * S - P + kw;
            avld[i] = (unsigned)ih < (unsigned)HIN && (unsigned)iw < (unsigned)WIN;
            abase[i] = avld[i] ? (((size_t)n_[i] * HIN + ih) * WIN + iw) * CIN : 0;
        }
        for (int ci0 = 0; ci0 < CIN; ci0 += 32) {
            int4 areg[2];
#pragma unroll
            for (int i = 0; i < 2; i++) {
                if (avld[i]) areg[i] = *(const int4*)(xin + abase[i] + ci0 + q * 8);
                else { areg[i].x = areg[i].y = areg[i].z = areg[i].w = 0; }
            }
            int4 breg[2];
            int nb = 0;
            for (int s = t; s < BN * 4; s += TPB) {
                int co = s >> 2, bq = s & 3;
                breg[nb++] = *(const int4*)(wrep + ((size_t)kk * COUT + co0 + co) * CIN + ci0 + bq * 8);
            }
            __syncthreads();
#pragma unroll
            for (int i = 0; i < 2; i++)
                *(int4*)&Ab[((t >> 2) + i * 64) * LDA + q * 8] = areg[i];
            nb = 0;
            for (int s = t; s < BN * 4; s += TPB) {
                int co = s >> 2, bq = s & 3;
                *(int4*)&Bb[co * LDA + bq * 8] = breg[nb++];
            }
            __syncthreads();

            const int koff = (lane >> 4) * 8, fr = lane & 15;
            v8s a[4], b[RN];
#pragma unroll
            for (int i = 0; i < 4; i++)
                a[i] = *(const v8s*)&Ab[(wm * 64 + i * 16 + fr) * LDA + koff];
#pragma unroll
            for (int j = 0; j < RN; j++)
                b[j] = *(const v8s*)&Bb[(wn * (BN / 2) + j * 16 + fr) * LDA + koff];
#pragma unroll
            for (int i = 0; i < 4; i++)
#pragma unroll
                for (int j = 0; j < RN; j++)
                    acc[i][j] = __builtin_amdgcn_mfma_f32_16x16x32_bf16(a[i], b[j], acc[i][j], 0, 0, 0);
        }
    }

#pragma unroll
    for (int i = 0; i < 4; i++) {
        int mr = wm * 64 + i * 16 + (lane >> 4) * 4;
#pragma unroll
        for (int j = 0; j < RN; j++) {
            int col = co0 + wn * (BN / 2) + j * 16 + (lane & 15);
            float bs = bias[col];
#pragma unroll
            for (int r = 0; r < 4; r++) {
                size_t g = (size_t)(m0 + mr + r) * COUT + col;
                float v = acc[i][j][r] + bs;
                if (OUT_F32) ((float*)yout)[g] = v;
                else ((unsigned short*)yout)[g] = f2us(v);
            }
        }
    }
}

// ---------------------------------------------------------------------------
// MFMA implicit-GEMM transposed conv, k4 s2 p1, parity-decomposed (4 classes,
// blockIdx.z). Weights pre-packed per class: [cls][kidx][COUT][CIN].
// ---------------------------------------------------------------------------
template<int CIN, int COUT, int HIN, int WIN, int BN>
__global__ __launch_bounds__(TPB) void convt_mfma(
    const unsigned short* __restrict__ xin, const unsigned short* __restrict__ wrep,
    const float* __restrict__ bias, unsigned short* __restrict__ yout, int N)
{
    constexpr int HOUT = HIN * 2, WOUT = WIN * 2;
    constexpr int LDA = 40;
    constexpr int RN = BN / 32;
    __shared__ __align__(16) unsigned short Ab[128 * LDA];
    __shared__ __align__(16) unsigned short Bb[BN * LDA];

    const int t = threadIdx.x, lane = t & 63, wave = t >> 6;
    const int wm = wave >> 1, wn = wave & 1;
    const int m0 = blockIdx.x * 128, co0 = blockIdx.y * BN;
    const int cls = blockIdx.z;
    const int ohp = cls >> 1, owp = cls & 1;
    const int khb = (ohp + 1) & 1, kwb = (owp + 1) & 1;
    const int dh0 = (ohp + 1 - khb) >> 1, dw0 = (owp + 1 - kwb) >> 1;
    const int q = t & 3;

    int n_[2], i_[2], j_[2];
#pragma unroll
    for (int i = 0; i < 2; i++) {
        int r = m0 + (t >> 2) + i * 64;
        n_[i] = r / (HIN * WIN);
        int rem = r % (HIN * WIN);
        i_[i] = rem / WIN;
        j_[i] = rem % WIN;
    }

    v4f acc[4][RN];
#pragma unroll
    for (int i = 0; i < 4; i++)
#pragma unroll
        for (int j = 0; j < RN; j++)
#pragma unroll
            for (int r = 0; r < 4; r++) acc[i][j][r] = 0.f;

    for (int kidx = 0; kidx < 4; kidx++) {
        const int dh = dh0 - (kidx >> 1);
        const int dw = dw0 - (kidx & 1);
        size_t abase[2];
        bool avld[2];
#pragma unroll
        for (int i = 0; i < 2; i++) {
            int ih = i_[i] + dh;
            int iw = j_[i] + dw;
            avld[i] = (unsigned)ih < (unsigned)HIN && (unsigned)iw < (unsigned)WIN;
            abase[i] = avld[i] ? (((size_t)n_[i] * HIN + ih) * WIN + iw) * CIN : 0;
        }
        const unsigned short* wk = wrep + (size_t)(cls * 4 + kidx) * COUT * CIN;
        for (int ci0 = 0; ci0 < CIN; ci0 += 32) {
            int4 areg[2];
#pragma unroll
            for (int i = 0; i < 2; i++) {
                if (avld[i]) areg[i] = *(const int4*)(xin + abase[i] + ci0 + q * 8);
                else { areg[i].x = areg[i].y = areg[i].z = areg[i].w = 0; }
            }
            int4 breg[2];
            int nb = 0;
            for (int s = t; s < BN * 4; s += TPB) {
                int co = s >> 2, bq = s & 3;
                breg[nb++] = *(const int4*)(wk + (size_t)(co0 + co) * CIN + ci0 + bq * 8);
            }
            __syncthreads();
#pragma unroll
            for (int i = 0; i < 2; i++)
                *(int4*)&Ab[((t >> 2) + i * 64) * LDA + q * 8] = areg[i];
            nb = 0;
            for (int s = t; s < BN * 4; s += TPB) {
                int co = s >> 2, bq = s & 3;
                *(int4*)&Bb[co * LDA + bq * 8] = breg[nb++];
            }
            __syncthreads();

            const int koff = (lane >> 4) * 8, fr = lane & 15;
            v8s a[4], b[RN];
#pragma unroll
            for (int i = 0; i < 4; i++)
                a[i] = *(const v8s*)&Ab[(wm * 64 + i * 16 + fr) * LDA + koff];
#pragma unroll
            for (int j = 0; j < RN; j++)
                b[j] = *(const v8s*)&Bb[(wn * (BN / 2) + j * 16 + fr) * LDA + koff];
#pragma unroll
            for (int i = 0; i < 4; i++)
#pragma unroll
                for (int j = 0; j < RN; j++)
                    acc[i][j] = __builtin_amdgcn_mfma_f32_16x16x32_bf16(a[i], b[j], acc[i][j], 0, 0, 0);
        }
    }

#pragma unroll
    for (int i = 0; i < 4; i++) {
        int mr = wm * 64 + i * 16 + (lane >> 4) * 4;
#pragma unroll
        for (int j = 0; j < RN; j++) {
            int col = co0 + wn * (BN / 2) + j * 16 + (lane & 15);
            float bs = bias[col];
#pragma unroll
            for (int r = 0; r < 4; r++) {
                int g = m0 + mr + r;                 // class-space row
                int n = g / (HIN * WIN);
                int rem = g % (HIN * WIN);
                int oh = 2 * (rem / WIN) + ohp;
                int ow = 2 * (rem % WIN) + owp;
                size_t gi = (((size_t)n * HOUT + oh) * WOUT + ow) * COUT + col;
                yout[gi] = f2us(acc[i][j][r] + bs);
            }
        }
    }
}

// ---------------------------------------------------------------------------
// BN stats over NHWC bf16: thread t -> channel t%C; atomics into zeroed ws.
// ---------------------------------------------------------------------------
template<int C>
__global__ __launch_bounds__(TPB) void bn_stats_b(
    const unsigned short* __restrict__ x, float* __restrict__ st, int M)
{
    constexpr int RPI = TPB / C;
    constexpr int ACT = RPI * C;
    int t = threadIdx.x;
    if (t >= ACT) return;
    int c = t % C, rs = t / C;
    float s = 0.f, sq = 0.f;
    for (int row = blockIdx.x * RPI + rs; row < M; row += gridDim.x * RPI) {
        float v = us2f(x[(size_t)row * C + c]);
        s += v;
        sq += v * v;
    }
    atomicAdd(&st[c], s);
    atomicAdd(&st[C + c], sq);
}

// In-place BN + ReLU on NHWC bf16 (2 elems per thread via uint).
template<int C>
__global__ __launch_bounds__(TPB) void bn_apply_b(
    unsigned short* __restrict__ x, const float* __restrict__ st,
    const float* __restrict__ g, const float* __restrict__ be, int M)
{
    int idx = blockIdx.x * TPB + threadIdx.x;
    int tot = M * (C / 2);
    if (idx >= tot) return;
    int c0 = (2 * idx) % C;
    float cnt = (float)M;
    float m0 = st[c0] / cnt, v0 = st[C + c0] / cnt - m0 * m0;
    float sc0 = g[c0] * rsqrtf(v0 + 1e-5f), sh0 = be[c0] - m0 * sc0;
    int c1 = c0 + 1;
    float m1 = st[c1] / cnt, v1 = st[C + c1] / cnt - m1 * m1;
    float sc1 = g[c1] * rsqrtf(v1 + 1e-5f), sh1 = be[c1] - m1 * sc1;
    unsigned int u = ((unsigned int*)x)[idx];
    float a = fmaxf(us2f(u & 0xffffu) * sc0 + sh0, 0.f);
    float b = fmaxf(us2f(u >> 16) * sc1 + sh1, 0.f);
    ((unsigned int*)x)[idx] = (unsigned int)f2us(a) | ((unsigned int)f2us(b) << 16);
}

// ---------------------------------------------------------------------------
// VQ on NHWC fp32 rows.
// ---------------------------------------------------------------------------
__global__ __launch_bounds__(TPB) void cb_transpose(
    const float* __restrict__ cb, float* __restrict__ cbT)
{
    int idx = blockIdx.x * TPB + threadIdx.x;
    int d = idx >> 8, c = idx & 255;
    cbT[idx] = cb[c * 256 + d];
}

__global__ __launch_bounds__(TPB) void vq_nhwc(
    const float* __restrict__ h4, const float* __restrict__ cbT,
    const float* __restrict__ cb, unsigned short* __restrict__ hq,
    float* __restrict__ lossp)
{
    int row = blockIdx.x;
    int t = threadIdx.x;
    __shared__ float zs[256];
    zs[t] = h4[(size_t)row * 256 + t];
    __syncthreads();
    float acc = 0.f;
#pragma unroll 4
    for (int d = 0; d < 256; d++) {
        float diff = zs[d] - cbT[d * 256 + t];
        acc += diff * diff;
    }
    __shared__ float sd[256];
    __shared__ int si[256];
    sd[t] = acc;
    si[t] = t;
    __syncthreads();
    for (int off = 128; off > 0; off >>= 1) {
        if (t < off) {
            float a = sd[t], b = sd[t + off];
            int ia = si[t], ib = si[t + off];
            if (b < a || (b == a && ib < ia)) { sd[t] = b; si[t] = ib; }
        }
        __syncthreads();
    }
    int j = si[0];
    if (t == 0) atomicAdd(&lossp[row & 63], sd[0]);
    hq[(size_t)row * 256 + t] = f2us(cb[(size_t)j * 256 + t]);
}

__global__ __launch_bounds__(64) void loss_finalize(
    const float* __restrict__ lossp, float* __restrict__ out2)
{
    float v = lossp[threadIdx.x];
    for (int off = 32; off > 0; off >>= 1) v += __shfl_down(v, off);
    if (threadIdx.x == 0) {
        float m = v * (1.0f / 32768.0f);
        out2[0] = m;
        out2[1] = m;
    }
}

// ---------------------------------------------------------------------------
// Decoder L4: direct conv 64->3, k3 s1 p1, NHWC bf16 in -> NCHW fp32 d_out.
// ---------------------------------------------------------------------------
__global__ __launch_bounds__(TPB) void conv_d4(
    const unsigned short* __restrict__ xb, const float* __restrict__ w,
    const float* __restrict__ bias, float* __restrict__ out, int N)
{
    __shared__ float wl[1728];   // [tap9][ci64][co3]
    int t = threadIdx.x;
    for (int i = t; i < 1728; i += TPB) {
        int co = i % 3, ci = (i / 3) % 64, tap = i / 192;
        wl[i] = w[((size_t)co * 64 + ci) * 9 + tap];
    }
    __syncthreads();
    int p = blockIdx.x * TPB + t;
    int n = p >> 12, oh = (p >> 6) & 63, ow = p & 63;
    float a0 = bias[0], a1 = bias[1], a2 = bias[2];
#pragma unroll
    for (int kh = 0; kh < 3; kh++) {
        int ih = oh - 1 + kh;
        if ((unsigned)ih >= 64u) continue;
#pragma unroll
        for (int kw = 0; kw < 3; kw++) {
            int iw = ow - 1 + kw;
            if ((unsigned)iw >= 64u) continue;
            const unsigned short* xp = xb + (((size_t)n * 64 + ih) * 64 + iw) * 64;
            int tap = kh * 3 + kw;
#pragma unroll
            for (int c8 = 0; c8 < 8; c8++) {
                int4 v = *(const int4*)(xp + c8 * 8);
                const unsigned int* vu = (const unsigned int*)&v;
#pragma unroll
                for (int k = 0; k < 4; k++) {
                    unsigned int u = vu[k];
                    float f0 = us2f(u & 0xffffu);
                    float f1 = us2f(u >> 16);
                    const float* wp = &wl[(tap * 64 + c8 * 8 + k * 2) * 3];
                    a0 += f0 * wp[0]; a1 += f0 * wp[1]; a2 += f0 * wp[2];
                    a0 += f1 * wp[3]; a1 += f1 * wp[4]; a2 += f1 * wp[5];
                }
            }
        }
    }
    size_t base = (size_t)n * 3 * 4096 + oh * 64 + ow;
    out[base] = a0;
    out[base + 4096] = a1;
    out[base + 8192] = a2;
}

// ---------------------------------------------------------------------------

extern "C" void kernel_launch(void* const* d_in, const int* in_sizes, int n_in,
                              void* d_out, int out_size, void* d_ws, size_t ws_size,
                              hipStream_t stream) {
    const float* x    = (const float*)d_in[0];
    const float* cb   = (const float*)d_in[1];
    const float* e_w1 = (const float*)d_in[2];  const float* e_b1 = (const float*)d_in[3];
    const float* e_g1 = (const float*)d_in[4];  const float* e_be1 = (const float*)d_in[5];
    const float* e_w2 = (const float*)d_in[6];  const float* e_b2 = (const float*)d_in[7];
    const float* e_g2 = (const float*)d_in[8];  const float* e_be2 = (const float*)d_in[9];
    const float* e_w3 = (const float*)d_in[10]; const float* e_b3 = (const float*)d_in[11];
    const float* e_g3 = (const float*)d_in[12]; const float* e_be3 = (const float*)d_in[13];
    const float* e_w4 = (const float*)d_in[14]; const float* e_b4 = (const float*)d_in[15];
    const float* d_w1 = (const float*)d_in[16]; const float* d_b1 = (const float*)d_in[17];
    const float* d_g1 = (const float*)d_in[18]; const float* d_be1 = (const float*)d_in[19];
    const float* d_w2 = (const float*)d_in[20]; const float* d_b2 = (const float*)d_in[21];
    const float* d_g2 = (const float*)d_in[22]; const float* d_be2 = (const float*)d_in[23];
    const float* d_w3 = (const float*)d_in[24]; const float* d_b3 = (const float*)d_in[25];
    const float* d_g3 = (const float*)d_in[26]; const float* d_be3 = (const float*)d_in[27];
    const float* d_w4 = (const float*)d_in[28]; const float* d_b4 = (const float*)d_in[29];

    float* ws = (float*)d_ws;
    // float-offset layout (total ~166 MB < 201 MB proven safe):
    // R1 [0, 16777216):        h1 bf16 (33.5M el) -> later g3
    // R2 [16777216, 25165824): h2 bf16 (16.8M el) -> later g2
    // R3 [25165824, 28311552): h3 bf16 (6.3M el)  -> later g1
    // H4F [28311552, 36700160): h4 fp32 (VQ input)
    // HQ  [36700160, 40894464): hq bf16 (8.4M el)
    // CBT [40894464, 40960000)
    // STATS [40960000, +3072), LOSSP [+64)
    // WREP bf16 base at float 40963136
    unsigned short* h1 = (unsigned short*)(ws);
    unsigned short* g3 = h1;
    unsigned short* h2 = (unsigned short*)(ws + 16777216);
    unsigned short* g2 = h2;
    unsigned short* h3 = (unsigned short*)(ws + 25165824);
    unsigned short* g1 = h3;
    float* h4f = ws + 28311552;
    unsigned short* hq = (unsigned short*)(ws + 36700160);
    float* cbT = ws + 40894464;
    float* stats = ws + 40960000;
    float* lossp = stats + 3072;
    unsigned short* wrep = (unsigned short*)(ws + 40963136);
    unsigned short* we2 = wrep + 0;        // 16*128*64   = 131072
    unsigned short* we3 = wrep + 131072;   // 16*192*128  = 393216
    unsigned short* we4 = wrep + 524288;   // 256*192     = 49152
    unsigned short* wd1 = wrep + 573440;   // 192*256     = 49152
    unsigned short* wd2 = wrep + 622592;   // 4*4*128*192 = 393216
    unsigned short* wd3 = wrep + 1015808;  // 4*4*64*128  = 131072
    float* out = (float*)d_out;
    float* losses = out + 1572864;

    const int N = 128;

    hipMemsetAsync(stats, 0, (3072 + 64) * sizeof(float), stream);

    // weight repacks (tiny)
    repack_w<64, 128, 16><<<512, TPB, 0, stream>>>(e_w2, we2);
    repack_w<128, 192, 16><<<1536, TPB, 0, stream>>>(e_w3, we3);
    repack_w<192, 256, 1><<<192, TPB, 0, stream>>>(e_w4, we4);
    repack_wt1<256, 192><<<192, TPB, 0, stream>>>(d_w1, wd1);
    repack_wct<192, 128><<<1536, TPB, 0, stream>>>(d_w2, wd2);
    repack_wct<128, 64><<<512, TPB, 0, stream>>>(d_w3, wd3);
    cb_transpose<<<256, TPB, 0, stream>>>(cb, cbT);

    // ---- E1: 3->64 k3 s1 p1 (direct) ----
    conv_e1<<<2048, TPB, 0, stream>>>(x, e_w1, e_b1, h1, N);
    bn_stats_b<64><<<256, TPB, 0, stream>>>(h1, stats + 0 * 512, 524288);
    bn_apply_b<64><<<65536, TPB, 0, stream>>>(h1, stats + 0 * 512, e_g1, e_be1, 524288);

    // ---- E2: 64->128 k4 s2 p1 (MFMA) ----
    conv_mfma<64, 128, 64, 64, 4, 2, 1, 128, 0>
        <<<dim3(1024, 1), TPB, 0, stream>>>(h1, we2, e_b2, h2, N);
    bn_stats_b<128><<<256, TPB, 0, stream>>>(h2, stats + 1 * 512, 131072);
    bn_apply_b<128><<<32768, TPB, 0, stream>>>(h2, stats + 1 * 512, e_g2, e_be2, 131072);

    // ---- E3: 128->192 k4 s2 p1 (MFMA) ----
    conv_mfma<128, 192, 32, 32, 4, 2, 1, 96, 0>
        <<<dim3(256, 2), TPB, 0, stream>>>(h2, we3, e_b3, h3, N);
    bn_stats_b<192><<<256, TPB, 0, stream>>>(h3, stats + 2 * 512, 32768);
    bn_apply_b<192><<<12288, TPB, 0, stream>>>(h3, stats + 2 * 512, e_g3, e_be3, 32768);

    // ---- E4: 192->256 1x1 (MFMA, fp32 out for VQ) ----
    conv_mfma<192, 256, 16, 16, 1, 1, 0, 128, 1>
        <<<dim3(256, 2), TPB, 0, stream>>>(h3, we4, e_b4, h4f, N);

    // ---- VQ ----
    vq_nhwc<<<32768, TPB, 0, stream>>>(h4f, cbT, cb, hq, lossp);
    loss_finalize<<<1, 64, 0, stream>>>(lossp, losses);

    // ---- D1: 256->192 1x1 convT (MFMA) ----
    conv_mfma<256, 192, 16, 16, 1, 1, 0, 96, 0>
        <<<dim3(256, 2), TPB, 0, stream>>>(hq, wd1, d_b1, g1, N);
    bn_stats_b<192><<<256, TPB, 0, stream>>>(g1, stats + 3 * 512, 32768);
    bn_apply_b<192><<<12288, TPB, 0, stream>>>(g1, stats + 3 * 512, d_g1, d_be1, 32768);

    // ---- D2: 192->128 convT k4 s2 p1 (MFMA, parity classes) ----
    convt_mfma<192, 128, 16, 16, 128>
        <<<dim3(256, 1, 4), TPB, 0, stream>>>(g1, wd2, d_b2, g2, N);
    bn_stats_b<128><<<256, TPB, 0, stream>>>(g2, stats + 4 * 512, 131072);
    bn_apply_b<128><<<32768, TPB, 0, stream>>>(g2, stats + 4 * 512, d_g2, d_be2, 131072);

    // ---- D3: 128->64 convT k4 s2 p1 (MFMA, parity classes) ----
    convt_mfma<128, 64, 32, 32, 64>
        <<<dim3(1024, 1, 4), TPB, 0, stream>>>(g2, wd3, d_b3, g3, N);
    bn_stats_b<64><<<256, TPB, 0, stream>>>(g3, stats + 5 * 512, 524288);
    bn_apply_b<64><<<65536, TPB, 0, stream>>>(g3, stats + 5 * 512, d_g3, d_be3, 524288);

    // ---- D4: 64->3 k3 s1 p1 (direct) -> NCHW fp32 d_out ----
    conv_d4<<<2048, TPB, 0, stream>>>(g3, d_w4, d_b4, out, N);
}

// Round 4
// 1220.827 us; speedup vs baseline: 13.8706x; 1.4141x over previous
//
#include <hip/hip_runtime.h>

#define TPB 256

typedef __attribute__((ext_vector_type(4))) float v4f;
typedef __attribute__((ext_vector_type(8))) short v8s;

__device__ __forceinline__ float us2f(unsigned int u) {
    union { unsigned int i; float f; } w; w.i = u << 16; return w.f;
}
__device__ __forceinline__ unsigned short f2us(float f) {
    union { float ff; unsigned int i; } w; w.ff = f;
    unsigned int u = w.i;
    return (unsigned short)((u + 0x7fffu + ((u >> 16) & 1u)) >> 16);
}

// ---------------------------------------------------------------------------
// Weight repacks (fp32 -> bf16, GEMM-friendly [tap][co][ci])
// ---------------------------------------------------------------------------
template<int CIN, int COUT, int KK>
__global__ __launch_bounds__(TPB) void repack_w(
    const float* __restrict__ w, unsigned short* __restrict__ o)
{
    int idx = blockIdx.x * TPB + threadIdx.x;
    if (idx >= KK * COUT * CIN) return;
    int ci = idx % CIN;
    int co = (idx / CIN) % COUT;
    int kk = idx / (CIN * COUT);
    o[idx] = f2us(w[((size_t)co * CIN + ci) * KK + kk]);
}
template<int CIN, int COUT>
__global__ __launch_bounds__(TPB) void repack_wt1(
    const float* __restrict__ w, unsigned short* __restrict__ o)
{
    int idx = blockIdx.x * TPB + threadIdx.x;
    if (idx >= CIN * COUT) return;
    int ci = idx % CIN;
    int co = idx / CIN;
    o[idx] = f2us(w[(size_t)ci * COUT + co]);
}
template<int CIN, int COUT>
__global__ __launch_bounds__(TPB) void repack_wct(
    const float* __restrict__ w, unsigned short* __restrict__ o)
{
    int idx = blockIdx.x * TPB + threadIdx.x;
    if (idx >= 16 * COUT * CIN) return;
    int ci = idx % CIN;
    int co = (idx / CIN) % COUT;
    int kidx = (idx / (CIN * COUT)) & 3;
    int cls = idx / (CIN * COUT * 4);
    int ohp = cls >> 1, owp = cls & 1;
    int kh = ((ohp + 1) & 1) + 2 * (kidx >> 1);
    int kw = ((owp + 1) & 1) + 2 * (kidx & 1);
    o[idx] = f2us(w[((size_t)ci * COUT + co) * 16 + kh * 4 + kw]);
}

// ---------------------------------------------------------------------------
// Encoder L1: direct conv 3->64, k3 s1 p1, NCHW fp32 x -> NHWC bf16.
// ---------------------------------------------------------------------------
__global__ __launch_bounds__(TPB) void conv_e1(
    const float* __restrict__ x, const float* __restrict__ w,
    const float* __restrict__ bias, unsigned short* __restrict__ y, int N)
{
    __shared__ float wl[27][64];
    int t = threadIdx.x;
    for (int i = t; i < 27 * 64; i += TPB) {
        int co = i & 63;
        int tap = i >> 6;
        int ci = tap / 9, kk = tap % 9;
        wl[tap][co] = w[((size_t)co * 3 + ci) * 9 + kk];
    }
    __syncthreads();
    int p = blockIdx.x * TPB + t;
    int n = p >> 12, oh = (p >> 6) & 63, ow = p & 63;
    float acc[64];
#pragma unroll
    for (int co = 0; co < 64; co++) acc[co] = bias[co];
    for (int ci = 0; ci < 3; ci++) {
#pragma unroll
        for (int kh = 0; kh < 3; kh++) {
            int ih = oh - 1 + kh;
            if ((unsigned)ih >= 64u) continue;
#pragma unroll
            for (int kw = 0; kw < 3; kw++) {
                int iw = ow - 1 + kw;
                if ((unsigned)iw >= 64u) continue;
                float xv = x[(((size_t)n * 3 + ci) * 64 + ih) * 64 + iw];
                int tap = ci * 9 + kh * 3 + kw;
#pragma unroll
                for (int co = 0; co < 64; co++) acc[co] += xv * wl[tap][co];
            }
        }
    }
    unsigned int* yp = (unsigned int*)(y + (size_t)p * 64);
#pragma unroll
    for (int co = 0; co < 64; co += 2)
        yp[co >> 1] = (unsigned int)f2us(acc[co]) | ((unsigned int)f2us(acc[co + 1]) << 16);
}

// ---------------------------------------------------------------------------
// MFMA implicit-GEMM conv. NHWC bf16 in, [KK][COUT][CIN] bf16 weights.
// ---------------------------------------------------------------------------
template<int CIN, int COUT, int HIN, int WIN, int K, int S, int P, int BN, int OUT_F32>
__global__ __launch_bounds__(TPB) void conv_mfma(
    const unsigned short* __restrict__ xin, const unsigned short* __restrict__ wrep,
    const float* __restrict__ bias, void* __restrict__ yout, int N)
{
    constexpr int HOUT = (HIN + 2 * P - K) / S + 1;
    constexpr int WOUT = (WIN + 2 * P - K) / S + 1;
    constexpr int LDA = 40;
    constexpr int RN = BN / 32;
    __shared__ __align__(16) unsigned short Ab[128 * LDA];
    __shared__ __align__(16) unsigned short Bb[BN * LDA];

    const int t = threadIdx.x, lane = t & 63, wave = t >> 6;
    const int wm = wave >> 1, wn = wave & 1;
    const int m0 = blockIdx.x * 128, co0 = blockIdx.y * BN;
    const int q = t & 3;

    int n_[2], oh_[2], ow_[2];
#pragma unroll
    for (int i = 0; i < 2; i++) {
        int r = m0 + (t >> 2) + i * 64;
        n_[i] = r / (HOUT * WOUT);
        int rem = r % (HOUT * WOUT);
        oh_[i] = rem / WOUT;
        ow_[i] = rem % WOUT;
    }

    v4f acc[4][RN];
#pragma unroll
    for (int i = 0; i < 4; i++)
#pragma unroll
        for (int j = 0; j < RN; j++)
#pragma unroll
            for (int r = 0; r < 4; r++) acc[i][j][r] = 0.f;

    for (int kk = 0; kk < K * K; kk++) {
        const int kh = kk / K, kw = kk % K;
        size_t abase[2];
        bool avld[2];
#pragma unroll
        for (int i = 0; i < 2; i++) {
            int ih = oh_[i] * S - P + kh;
            int iw = ow_[i] * S - P + kw;
            avld[i] = (unsigned)ih < (unsigned)HIN && (unsigned)iw < (unsigned)WIN;
            abase[i] = avld[i] ? (((size_t)n_[i] * HIN + ih) * WIN + iw) * CIN : 0;
        }
        for (int ci0 = 0; ci0 < CIN; ci0 += 32) {
            int4 areg[2];
#pragma unroll
            for (int i = 0; i < 2; i++) {
                if (avld[i]) areg[i] = *(const int4*)(xin + abase[i] + ci0 + q * 8);
                else { areg[i].x = areg[i].y = areg[i].z = areg[i].w = 0; }
            }
            int4 breg[2];
            int nb = 0;
            for (int s = t; s < BN * 4; s += TPB) {
                int co = s >> 2, bq = s & 3;
                breg[nb++] = *(const int4*)(wrep + ((size_t)kk * COUT + co0 + co) * CIN + ci0 + bq * 8);
            }
            __syncthreads();
#pragma unroll
            for (int i = 0; i < 2; i++)
                *(int4*)&Ab[((t >> 2) + i * 64) * LDA + q * 8] = areg[i];
            nb = 0;
            for (int s = t; s < BN * 4; s += TPB) {
                int co = s >> 2, bq = s & 3;
                *(int4*)&Bb[co * LDA + bq * 8] = breg[nb++];
            }
            __syncthreads();

            const int koff = (lane >> 4) * 8, fr = lane & 15;
            v8s a[4], b[RN];
#pragma unroll
            for (int i = 0; i < 4; i++)
                a[i] = *(const v8s*)&Ab[(wm * 64 + i * 16 + fr) * LDA + koff];
#pragma unroll
            for (int j = 0; j < RN; j++)
                b[j] = *(const v8s*)&Bb[(wn * (BN / 2) + j * 16 + fr) * LDA + koff];
#pragma unroll
            for (int i = 0; i < 4; i++)
#pragma unroll
                for (int j = 0; j < RN; j++)
                    acc[i][j] = __builtin_amdgcn_mfma_f32_16x16x32_bf16(a[i], b[j], acc[i][j], 0, 0, 0);
        }
    }

#pragma unroll
    for (int i = 0; i < 4; i++) {
        int mr = wm * 64 + i * 16 + (lane >> 4) * 4;
#pragma unroll
        for (int j = 0; j < RN; j++) {
            int col = co0 + wn * (BN / 2) + j * 16 + (lane & 15);
            float bs = bias[col];
#pragma unroll
            for (int r = 0; r < 4; r++) {
                size_t g = (size_t)(m0 + mr + r) * COUT + col;
                float v = acc[i][j][r] + bs;
                if (OUT_F32) ((float*)yout)[g] = v;
                else ((unsigned short*)yout)[g] = f2us(v);
            }
        }
    }
}

// ---------------------------------------------------------------------------
// MFMA implicit-GEMM transposed conv, k4 s2 p1, parity-decomposed.
// ---------------------------------------------------------------------------
template<int CIN, int COUT, int HIN, int WIN, int BN>
__global__ __launch_bounds__(TPB) void convt_mfma(
    const unsigned short* __restrict__ xin, const unsigned short* __restrict__ wrep,
    const float* __restrict__ bias, unsigned short* __restrict__ yout, int N)
{
    constexpr int HOUT = HIN * 2, WOUT = WIN * 2;
    constexpr int LDA = 40;
    constexpr int RN = BN / 32;
    __shared__ __align__(16) unsigned short Ab[128 * LDA];
    __shared__ __align__(16) unsigned short Bb[BN * LDA];

    const int t = threadIdx.x, lane = t & 63, wave = t >> 6;
    const int wm = wave >> 1, wn = wave & 1;
    const int m0 = blockIdx.x * 128, co0 = blockIdx.y * BN;
    const int cls = blockIdx.z;
    const int ohp = cls >> 1, owp = cls & 1;
    const int khb = (ohp + 1) & 1, kwb = (owp + 1) & 1;
    const int dh0 = (ohp + 1 - khb) >> 1, dw0 = (owp + 1 - kwb) >> 1;
    const int q = t & 3;

    int n_[2], i_[2], j_[2];
#pragma unroll
    for (int i = 0; i < 2; i++) {
        int r = m0 + (t >> 2) + i * 64;
        n_[i] = r / (HIN * WIN);
        int rem = r % (HIN * WIN);
        i_[i] = rem / WIN;
        j_[i] = rem % WIN;
    }

    v4f acc[4][RN];
#pragma unroll
    for (int i = 0; i < 4; i++)
#pragma unroll
        for (int j = 0; j < RN; j++)
#pragma unroll
            for (int r = 0; r < 4; r++) acc[i][j][r] = 0.f;

    for (int kidx = 0; kidx < 4; kidx++) {
        const int dh = dh0 - (kidx >> 1);
        const int dw = dw0 - (kidx & 1);
        size_t abase[2];
        bool avld[2];
#pragma unroll
        for (int i = 0; i < 2; i++) {
            int ih = i_[i] + dh;
            int iw = j_[i] + dw;
            avld[i] = (unsigned)ih < (unsigned)HIN && (unsigned)iw < (unsigned)WIN;
            abase[i] = avld[i] ? (((size_t)n_[i] * HIN + ih) * WIN + iw) * CIN : 0;
        }
        const unsigned short* wk = wrep + (size_t)(cls * 4 + kidx) * COUT * CIN;
        for (int ci0 = 0; ci0 < CIN; ci0 += 32) {
            int4 areg[2];
#pragma unroll
            for (int i = 0; i < 2; i++) {
                if (avld[i]) areg[i] = *(const int4*)(xin + abase[i] + ci0 + q * 8);
                else { areg[i].x = areg[i].y = areg[i].z = areg[i].w = 0; }
            }
            int4 breg[2];
            int nb = 0;
            for (int s = t; s < BN * 4; s += TPB) {
                int co = s >> 2, bq = s & 3;
                breg[nb++] = *(const int4*)(wk + (size_t)(co0 + co) * CIN + ci0 + bq * 8);
            }
            __syncthreads();
#pragma unroll
            for (int i = 0; i < 2; i++)
                *(int4*)&Ab[((t >> 2) + i * 64) * LDA + q * 8] = areg[i];
            nb = 0;
            for (int s = t; s < BN * 4; s += TPB) {
                int co = s >> 2, bq = s & 3;
                *(int4*)&Bb[co * LDA + bq * 8] = breg[nb++];
            }
            __syncthreads();

            const int koff = (lane >> 4) * 8, fr = lane & 15;
            v8s a[4], b[RN];
#pragma unroll
            for (int i = 0; i < 4; i++)
                a[i] = *(const v8s*)&Ab[(wm * 64 + i * 16 + fr) * LDA + koff];
#pragma unroll
            for (int j = 0; j < RN; j++)
                b[j] = *(const v8s*)&Bb[(wn * (BN / 2) + j * 16 + fr) * LDA + koff];
#pragma unroll
            for (int i = 0; i < 4; i++)
#pragma unroll
                for (int j = 0; j < RN; j++)
                    acc[i][j] = __builtin_amdgcn_mfma_f32_16x16x32_bf16(a[i], b[j], acc[i][j], 0, 0, 0);
        }
    }

#pragma unroll
    for (int i = 0; i < 4; i++) {
        int mr = wm * 64 + i * 16 + (lane >> 4) * 4;
#pragma unroll
        for (int j = 0; j < RN; j++) {
            int col = co0 + wn * (BN / 2) + j * 16 + (lane & 15);
            float bs = bias[col];
#pragma unroll
            for (int r = 0; r < 4; r++) {
                int g = m0 + mr + r;
                int n = g / (HIN * WIN);
                int rem = g % (HIN * WIN);
                int oh = 2 * (rem / WIN) + ohp;
                int ow = 2 * (rem % WIN) + owp;
                size_t gi = (((size_t)n * HOUT + oh) * WOUT + ow) * COUT + col;
                yout[gi] = f2us(acc[i][j][r] + bs);
            }
        }
    }
}

// ---------------------------------------------------------------------------
// BN stats, vectorized: each thread owns a fixed group of 8 consecutive
// channels, loads int4 (16B/lane). Block-level LDS combine, then global atomics.
// ---------------------------------------------------------------------------
template<int C>
__global__ __launch_bounds__(TPB) void bn_stats_v(
    const unsigned short* __restrict__ x, float* __restrict__ st, int M)
{
    constexpr int GPT = C / 8;          // 8-ch groups per row
    constexpr int RPB = TPB / GPT;      // rows per block-iter
    constexpr int ACT = RPB * GPT;
    __shared__ float sred[2 * C];
    int t = threadIdx.x;
    for (int i = t; i < 2 * C; i += TPB) sred[i] = 0.f;
    __syncthreads();
    if (t < ACT) {
        int g = t % GPT, rs = t / GPT;
        float s[8], sq[8];
#pragma unroll
        for (int k = 0; k < 8; k++) { s[k] = 0.f; sq[k] = 0.f; }
        for (int row = blockIdx.x * RPB + rs; row < M; row += gridDim.x * RPB) {
            int4 v = *(const int4*)(x + (size_t)row * C + g * 8);
            const unsigned int* vu = (const unsigned int*)&v;
#pragma unroll
            for (int k = 0; k < 4; k++) {
                float f0 = us2f(vu[k] & 0xffffu);
                float f1 = us2f(vu[k] >> 16);
                s[2 * k] += f0; sq[2 * k] += f0 * f0;
                s[2 * k + 1] += f1; sq[2 * k + 1] += f1 * f1;
            }
        }
        int c0 = g * 8;
#pragma unroll
        for (int k = 0; k < 8; k++) {
            atomicAdd(&sred[c0 + k], s[k]);
            atomicAdd(&sred[C + c0 + k], sq[k]);
        }
    }
    __syncthreads();
    for (int i = t; i < 2 * C; i += TPB) atomicAdd(&st[i], sred[i]);
}

// In-place BN + ReLU on NHWC bf16, int4 (8 ch) per thread; scale/shift in LDS.
template<int C>
__global__ __launch_bounds__(TPB) void bn_apply_v(
    unsigned short* __restrict__ x, const float* __restrict__ st,
    const float* __restrict__ g, const float* __restrict__ be, int M)
{
    __shared__ float sc[C], sh[C];
    int t = threadIdx.x;
    float cnt = (float)M;
    for (int c = t; c < C; c += TPB) {
        float m = st[c] / cnt;
        float v = st[C + c] / cnt - m * m;
        float s = g[c] * rsqrtf(v + 1e-5f);
        sc[c] = s;
        sh[c] = be[c] - m * s;
    }
    __syncthreads();
    constexpr int GPT = C / 8;
    size_t tot = (size_t)M * GPT;
    for (size_t slot = (size_t)blockIdx.x * TPB + t; slot < tot;
         slot += (size_t)gridDim.x * TPB) {
        int c0 = (int)(slot % GPT) * 8;
        int4 v = *(int4*)(x + slot * 8);
        unsigned int* vu = (unsigned int*)&v;
#pragma unroll
        for (int k = 0; k < 4; k++) {
            float f0 = fmaxf(us2f(vu[k] & 0xffffu) * sc[c0 + 2 * k] + sh[c0 + 2 * k], 0.f);
            float f1 = fmaxf(us2f(vu[k] >> 16) * sc[c0 + 2 * k + 1] + sh[c0 + 2 * k + 1], 0.f);
            vu[k] = (unsigned int)f2us(f0) | ((unsigned int)f2us(f1) << 16);
        }
        *(int4*)(x + slot * 8) = v;
    }
}

// ---------------------------------------------------------------------------
// VQ stage 1: codebook prep — split fp32 -> (hi, lo) bf16, plus cn2[j]=||c_j||².
// ---------------------------------------------------------------------------
__global__ __launch_bounds__(TPB) void cb_prep(
    const float* __restrict__ cb, unsigned short* __restrict__ chb,
    unsigned short* __restrict__ clb, float* __restrict__ cn2)
{
    int j = blockIdx.x, d = threadIdx.x;
    float v = cb[j * 256 + d];
    unsigned short h = f2us(v);
    chb[j * 256 + d] = h;
    clb[j * 256 + d] = f2us(v - us2f(h));
    float s = v * v;
#pragma unroll
    for (int off = 1; off < 64; off <<= 1) s += __shfl_xor(s, off);
    __shared__ float p[4];
    if ((d & 63) == 0) p[d >> 6] = s;
    __syncthreads();
    if (d == 0) cn2[j] = p[0] + p[1] + p[2] + p[3];
}

// ---------------------------------------------------------------------------
// VQ stage 2: D[row][j] = cn2[j] - 2 * Z·C_j via split-bf16 MFMA GEMM.
// Z fp32 is hi/lo-split on the fly during A staging. 3 MFMAs per frag pair
// (hh + hl + lh); dropped ll term is ~2^-18 relative.
// ---------------------------------------------------------------------------
__global__ __launch_bounds__(TPB) void vq_gemm(
    const float* __restrict__ z, const unsigned short* __restrict__ chb,
    const unsigned short* __restrict__ clb, const float* __restrict__ cn2,
    float* __restrict__ D)
{
    constexpr int LDA = 40;
    __shared__ __align__(16) unsigned short Ah[128 * LDA];
    __shared__ __align__(16) unsigned short Al[128 * LDA];
    __shared__ __align__(16) unsigned short Bh[128 * LDA];
    __shared__ __align__(16) unsigned short Bl[128 * LDA];

    const int t = threadIdx.x, lane = t & 63, wave = t >> 6;
    const int wm = wave >> 1, wn = wave & 1;
    const int m0 = blockIdx.x * 128, co0 = blockIdx.y * 128;
    const int q = t & 3, rs = t >> 2;

    v4f acc[4][4];
#pragma unroll
    for (int i = 0; i < 4; i++)
#pragma unroll
        for (int j = 0; j < 4; j++)
#pragma unroll
            for (int r = 0; r < 4; r++) acc[i][j][r] = 0.f;

    for (int ci0 = 0; ci0 < 256; ci0 += 32) {
        unsigned int ah[2][4], al[2][4];
#pragma unroll
        for (int i = 0; i < 2; i++) {
            const float* zp = z + (size_t)(m0 + rs + i * 64) * 256 + ci0 + q * 8;
            float4 f0 = *(const float4*)zp;
            float4 f1 = *(const float4*)(zp + 4);
            float f[8] = {f0.x, f0.y, f0.z, f0.w, f1.x, f1.y, f1.z, f1.w};
#pragma unroll
            for (int k = 0; k < 4; k++) {
                unsigned short h0 = f2us(f[2 * k]);
                unsigned short h1 = f2us(f[2 * k + 1]);
                unsigned short l0 = f2us(f[2 * k] - us2f(h0));
                unsigned short l1 = f2us(f[2 * k + 1] - us2f(h1));
                ah[i][k] = (unsigned int)h0 | ((unsigned int)h1 << 16);
                al[i][k] = (unsigned int)l0 | ((unsigned int)l1 << 16);
            }
        }
        int4 bh[2], bl[2];
#pragma unroll
        for (int i = 0; i < 2; i++) {
            int s = t + i * 256;
            int co = s >> 2, bq = s & 3;
            bh[i] = *(const int4*)(chb + (size_t)(co0 + co) * 256 + ci0 + bq * 8);
            bl[i] = *(const int4*)(clb + (size_t)(co0 + co) * 256 + ci0 + bq * 8);
        }
        __syncthreads();
#pragma unroll
        for (int i = 0; i < 2; i++) {
            *(int4*)&Ah[(rs + i * 64) * LDA + q * 8] = *(int4*)ah[i];
            *(int4*)&Al[(rs + i * 64) * LDA + q * 8] = *(int4*)al[i];
        }
#pragma unroll
        for (int i = 0; i < 2; i++) {
            int s = t + i * 256;
            int co = s >> 2, bq = s & 3;
            *(int4*)&Bh[co * LDA + bq * 8] = bh[i];
            *(int4*)&Bl[co * LDA + bq * 8] = bl[i];
        }
        __syncthreads();

        const int koff = (lane >> 4) * 8, fr = lane & 15;
        v8s a_h[4], a_l[4], b_h[4], b_l[4];
#pragma unroll
        for (int i = 0; i < 4; i++) {
            a_h[i] = *(const v8s*)&Ah[(wm * 64 + i * 16 + fr) * LDA + koff];
            a_l[i] = *(const v8s*)&Al[(wm * 64 + i * 16 + fr) * LDA + koff];
        }
#pragma unroll
        for (int j = 0; j < 4; j++) {
            b_h[j] = *(const v8s*)&Bh[(wn * 64 + j * 16 + fr) * LDA + koff];
            b_l[j] = *(const v8s*)&Bl[(wn * 64 + j * 16 + fr) * LDA + koff];
        }
#pragma unroll
        for (int i = 0; i < 4; i++)
#pragma unroll
            for (int j = 0; j < 4; j++) {
                acc[i][j] = __builtin_amdgcn_mfma_f32_16x16x32_bf16(a_h[i], b_h[j], acc[i][j], 0, 0, 0);
                acc[i][j] = __builtin_amdgcn_mfma_f32_16x16x32_bf16(a_h[i], b_l[j], acc[i][j], 0, 0, 0);
                acc[i][j] = __builtin_amdgcn_mfma_f32_16x16x32_bf16(a_l[i], b_h[j], acc[i][j], 0, 0, 0);
            }
    }

#pragma unroll
    for (int i = 0; i < 4; i++) {
        int mr = wm * 64 + i * 16 + (lane >> 4) * 4;
#pragma unroll
        for (int j = 0; j < 4; j++) {
            int col = co0 + wn * 64 + j * 16 + (lane & 15);
            float c2 = cn2[col];
#pragma unroll
            for (int r = 0; r < 4; r++)
                D[(size_t)(m0 + mr + r) * 256 + col] = c2 - 2.f * acc[i][j][r];
        }
    }
}

// ---------------------------------------------------------------------------
// VQ stage 3: per-row argmin (wave per row, float4 loads, lex-min = first idx).
// ---------------------------------------------------------------------------
__global__ __launch_bounds__(TPB) void vq_argmin(
    const float* __restrict__ D, int* __restrict__ idxb)
{
    int row = blockIdx.x * 4 + (threadIdx.x >> 6);
    int lane = threadIdx.x & 63;
    float4 v = *(const float4*)(D + (size_t)row * 256 + lane * 4);
    float best = v.x; int bi = lane * 4;
    if (v.y < best) { best = v.y; bi = lane * 4 + 1; }
    if (v.z < best) { best = v.z; bi = lane * 4 + 2; }
    if (v.w < best) { best = v.w; bi = lane * 4 + 3; }
#pragma unroll
    for (int off = 1; off < 64; off <<= 1) {
        float ov = __shfl_xor(best, off);
        int oi = __shfl_xor(bi, off);
        if (ov < best || (ov == best && oi < bi)) { best = ov; bi = oi; }
    }
    if (lane == 0) idxb[row] = bi;
}

// ---------------------------------------------------------------------------
// VQ stage 4: gather chosen code -> hq (bf16), exact fp32 loss accumulation.
// ---------------------------------------------------------------------------
__global__ __launch_bounds__(TPB) void vq_gather(
    const float* __restrict__ z, const float* __restrict__ cb,
    const int* __restrict__ idxb, unsigned short* __restrict__ hq,
    float* __restrict__ lossp)
{
    int row = blockIdx.x, t = threadIdx.x;
    int j = idxb[row];
    float zv = z[(size_t)row * 256 + t];
    float cv = cb[(size_t)j * 256 + t];
    float d = zv - cv;
    d = d * d;
#pragma unroll
    for (int off = 1; off < 64; off <<= 1) d += __shfl_xor(d, off);
    __shared__ float p[4];
    if ((t & 63) == 0) p[t >> 6] = d;
    __syncthreads();
    if (t == 0) atomicAdd(&lossp[row & 63], p[0] + p[1] + p[2] + p[3]);
    hq[(size_t)row * 256 + t] = f2us(cv);
}

__global__ __launch_bounds__(64) void loss_finalize(
    const float* __restrict__ lossp, float* __restrict__ out2)
{
    float v = lossp[threadIdx.x];
    for (int off = 32; off > 0; off >>= 1) v += __shfl_down(v, off);
    if (threadIdx.x == 0) {
        float m = v * (1.0f / 32768.0f);
        out2[0] = m;
        out2[1] = m;
    }
}

// ---------------------------------------------------------------------------
// Decoder L4: direct conv 64->3, k3 s1 p1, NHWC bf16 in -> NCHW fp32 d_out.
// ---------------------------------------------------------------------------
__global__ __launch_bounds__(TPB) void conv_d4(
    const unsigned short* __restrict__ xb, const float* __restrict__ w,
    const float* __restrict__ bias, float* __restrict__ out, int N)
{
    __shared__ float wl[1728];
    int t = threadIdx.x;
    for (int i = t; i < 1728; i += TPB) {
        int co = i % 3, ci = (i / 3) % 64, tap = i / 192;
        wl[i] = w[((size_t)co * 64 + ci) * 9 + tap];
    }
    __syncthreads();
    int p = blockIdx.x * TPB + t;
    int n = p >> 12, oh = (p >> 6) & 63, ow = p & 63;
    float a0 = bias[0], a1 = bias[1], a2 = bias[2];
#pragma unroll
    for (int kh = 0; kh < 3; kh++) {
        int ih = oh - 1 + kh;
        if ((unsigned)ih >= 64u) continue;
#pragma unroll
        for (int kw = 0; kw < 3; kw++) {
            int iw = ow - 1 + kw;
            if ((unsigned)iw >= 64u) continue;
            const unsigned short* xp = xb + (((size_t)n * 64 + ih) * 64 + iw) * 64;
            int tap = kh * 3 + kw;
#pragma unroll
            for (int c8 = 0; c8 < 8; c8++) {
                int4 v = *(const int4*)(xp + c8 * 8);
                const unsigned int* vu = (const unsigned int*)&v;
#pragma unroll
                for (int k = 0; k < 4; k++) {
                    unsigned int u = vu[k];
                    float f0 = us2f(u & 0xffffu);
                    float f1 = us2f(u >> 16);
                    const float* wp = &wl[(tap * 64 + c8 * 8 + k * 2) * 3];
                    a0 += f0 * wp[0]; a1 += f0 * wp[1]; a2 += f0 * wp[2];
                    a0 += f1 * wp[3]; a1 += f1 * wp[4]; a2 += f1 * wp[5];
                }
            }
        }
    }
    size_t base = (size_t)n * 3 * 4096 + oh * 64 + ow;
    out[base] = a0;
    out[base + 4096] = a1;
    out[base + 8192] = a2;
}

// ---------------------------------------------------------------------------

extern "C" void kernel_launch(void* const* d_in, const int* in_sizes, int n_in,
                              void* d_out, int out_size, void* d_ws, size_t ws_size,
                              hipStream_t stream) {
    const float* x    = (const float*)d_in[0];
    const float* cb   = (const float*)d_in[1];
    const float* e_w1 = (const float*)d_in[2];  const float* e_b1 = (const float*)d_in[3];
    const float* e_g1 = (const float*)d_in[4];  const float* e_be1 = (const float*)d_in[5];
    const float* e_w2 = (const float*)d_in[6];  const float* e_b2 = (const float*)d_in[7];
    const float* e_g2 = (const float*)d_in[8];  const float* e_be2 = (const float*)d_in[9];
    const float* e_w3 = (const float*)d_in[10]; const float* e_b3 = (const float*)d_in[11];
    const float* e_g3 = (const float*)d_in[12]; const float* e_be3 = (const float*)d_in[13];
    const float* e_w4 = (const float*)d_in[14]; const float* e_b4 = (const float*)d_in[15];
    const float* d_w1 = (const float*)d_in[16]; const float* d_b1 = (const float*)d_in[17];
    const float* d_g1 = (const float*)d_in[18]; const float* d_be1 = (const float*)d_in[19];
    const float* d_w2 = (const float*)d_in[20]; const float* d_b2 = (const float*)d_in[21];
    const float* d_g2 = (const float*)d_in[22]; const float* d_be2 = (const float*)d_in[23];
    const float* d_w3 = (const float*)d_in[24]; const float* d_b3 = (const float*)d_in[25];
    const float* d_g3 = (const float*)d_in[26]; const float* d_be3 = (const float*)d_in[27];
    const float* d_w4 = (const float*)d_in[28]; const float* d_b4 = (const float*)d_in[29];

    float* ws = (float*)d_ws;
    // float-offset layout (~200 MB, < 201.3 MB proven safe in round 1):
    unsigned short* h1 = (unsigned short*)(ws);              // [0, 16777216)
    unsigned short* g3 = h1;
    unsigned short* h2 = (unsigned short*)(ws + 16777216);   // [.., 25165824)
    unsigned short* g2 = h2;
    unsigned short* h3 = (unsigned short*)(ws + 25165824);   // [.., 28311552)
    unsigned short* g1 = h3;
    float* h4f = ws + 28311552;                              // [.., 36700160)
    unsigned short* hq = (unsigned short*)(ws + 36700160);   // [.., 40894464)
    float* stats = ws + 40960000;                            // 3072
    float* lossp = ws + 40963072;                            // 64
    int* idxb = (int*)(ws + 40963136);                       // 32768
    float* cn2 = ws + 40995904;                              // 256
    unsigned short* chb = (unsigned short*)(ws + 40996160);  // 65536 shorts
    unsigned short* clb = (unsigned short*)(ws + 41028928);  // 65536 shorts
    unsigned short* wrep = (unsigned short*)(ws + 41061696);
    unsigned short* we2 = wrep + 0;        // 16*128*64   = 131072
    unsigned short* we3 = wrep + 131072;   // 16*192*128  = 393216
    unsigned short* we4 = wrep + 524288;   // 256*192     = 49152
    unsigned short* wd1 = wrep + 573440;   // 192*256     = 49152
    unsigned short* wd2 = wrep + 622592;   // 4*4*128*192 = 393216
    unsigned short* wd3 = wrep + 1015808;  // 4*4*64*128  = 131072
    float* Dscr = ws + 41635136;                             // 8388608 floats
    float* out = (float*)d_out;
    float* losses = out + 1572864;

    const int N = 128;

    hipMemsetAsync(stats, 0, (3072 + 64) * sizeof(float), stream);

    // weight / codebook prep (tiny)
    repack_w<64, 128, 16><<<512, TPB, 0, stream>>>(e_w2, we2);
    repack_w<128, 192, 16><<<1536, TPB, 0, stream>>>(e_w3, we3);
    repack_w<192, 256, 1><<<192, TPB, 0, stream>>>(e_w4, we4);
    repack_wt1<256, 192><<<192, TPB, 0, stream>>>(d_w1, wd1);
    repack_wct<192, 128><<<1536, TPB, 0, stream>>>(d_w2, wd2);
    repack_wct<128, 64><<<512, TPB, 0, stream>>>(d_w3, wd3);
    cb_prep<<<256, TPB, 0, stream>>>(cb, chb, clb, cn2);

    // ---- E1: 3->64 k3 s1 p1 (direct) ----
    conv_e1<<<2048, TPB, 0, stream>>>(x, e_w1, e_b1, h1, N);
    bn_stats_v<64><<<512, TPB, 0, stream>>>(h1, stats + 0 * 512, 524288);
    bn_apply_v<64><<<4096, TPB, 0, stream>>>(h1, stats + 0 * 512, e_g1, e_be1, 524288);

    // ---- E2: 64->128 k4 s2 p1 (MFMA) ----
    conv_mfma<64, 128, 64, 64, 4, 2, 1, 128, 0>
        <<<dim3(1024, 1), TPB, 0, stream>>>(h1, we2, e_b2, h2, N);
    bn_stats_v<128><<<256, TPB, 0, stream>>>(h2, stats + 1 * 512, 131072);
    bn_apply_v<128><<<2048, TPB, 0, stream>>>(h2, stats + 1 * 512, e_g2, e_be2, 131072);

    // ---- E3: 128->192 k4 s2 p1 (MFMA) ----
    conv_mfma<128, 192, 32, 32, 4, 2, 1, 96, 0>
        <<<dim3(256, 2), TPB, 0, stream>>>(h2, we3, e_b3, h3, N);
    bn_stats_v<192><<<128, TPB, 0, stream>>>(h3, stats + 2 * 512, 32768);
    bn_apply_v<192><<<1024, TPB, 0, stream>>>(h3, stats + 2 * 512, e_g3, e_be3, 32768);

    // ---- E4: 192->256 1x1 (MFMA, fp32 out for VQ) ----
    conv_mfma<192, 256, 16, 16, 1, 1, 0, 128, 1>
        <<<dim3(256, 2), TPB, 0, stream>>>(h3, we4, e_b4, h4f, N);

    // ---- VQ: GEMM distances -> argmin -> gather/loss ----
    vq_gemm<<<dim3(256, 2), TPB, 0, stream>>>(h4f, chb, clb, cn2, Dscr);
    vq_argmin<<<8192, TPB, 0, stream>>>(Dscr, idxb);
    vq_gather<<<32768, TPB, 0, stream>>>(h4f, cb, idxb, hq, lossp);
    loss_finalize<<<1, 64, 0, stream>>>(lossp, losses);

    // ---- D1: 256->192 1x1 convT (MFMA) ----
    conv_mfma<256, 192, 16, 16, 1, 1, 0, 96, 0>
        <<<dim3(256, 2), TPB, 0, stream>>>(hq, wd1, d_b1, g1, N);
    bn_stats_v<192><<<128, TPB, 0, stream>>>(g1, stats + 3 * 512, 32768);
    bn_apply_v<192><<<1024, TPB, 0, stream>>>(g1, stats + 3 * 512, d_g1, d_be1, 32768);

    // ---- D2: 192->128 convT k4 s2 p1 (MFMA, parity classes) ----
    convt_mfma<192, 128, 16, 16, 128>
        <<<dim3(256, 1, 4), TPB, 0, stream>>>(g1, wd2, d_b2, g2, N);
    bn_stats_v<128><<<256, TPB, 0, stream>>>(g2, stats + 4 * 512, 131072);
    bn_apply_v<128><<<2048, TPB, 0, stream>>>(g2, stats + 4 * 512, d_g2, d_be2, 131072);

    // ---- D3: 128->64 convT k4 s2 p1 (MFMA, parity classes) ----
    convt_mfma<128, 64, 32, 32, 64>
        <<<dim3(1024, 1, 4), TPB, 0, stream>>>(g2, wd3, d_b3, g3, N);
    bn_stats_v<64><<<512, TPB, 0, stream>>>(g3, stats + 5 * 512, 524288);
    bn_apply_v<64><<<4096, TPB, 0, stream>>>(g3, stats + 5 * 512, d_g3, d_be3, 524288);

    // ---- D4: 64->3 k3 s1 p1 (direct) -> NCHW fp32 d_out ----
    conv_d4<<<2048, TPB, 0, stream>>>(g3, d_w4, d_b4, out, N);
}